// Round 1
// baseline (1505.612 us; speedup 1.0000x reference)
//
#include <hip/hip_runtime.h>

#define H_  2048
#define BS_ 128
#define NB_ 44
#define R_  64
#define K_  8
#define N_  8192
#define I_  5632
#define MT  64
#define TILES 32   // capacity per block = 2048 pairs (mean 1489, max ~1650)

typedef __bf16 bf16x8 __attribute__((ext_vector_type(8)));
typedef float  f32x4  __attribute__((ext_vector_type(4)));

__device__ __forceinline__ unsigned short f2bf(float f) {
  unsigned int u = __float_as_uint(f);
  u = (u + 0x7FFFu + ((u >> 16) & 1u)) >> 16;   // RNE, inputs finite
  return (unsigned short)u;
}
__device__ __forceinline__ float bf2f(unsigned short s) {
  return __uint_as_float(((unsigned int)s) << 16);
}
__device__ __forceinline__ bf16x8 ld8(const unsigned short* p) {
  uint4 v = *reinterpret_cast<const uint4*>(p);
  return __builtin_bit_cast(bf16x8, v);
}

// ---------------- init: out = comp_bias (broadcast), zero counts ----------
__global__ void init_out_kernel(float* __restrict__ out,
                                const float* __restrict__ cbias,
                                int* __restrict__ counts) {
  if (blockIdx.x == 0 && threadIdx.x < NB_) counts[threadIdx.x] = 0;
  int stride = gridDim.x * blockDim.x;
  int n4 = N_ * H_ / 4;
  for (int i = blockIdx.x * blockDim.x + threadIdx.x; i < n4; i += stride) {
    int h = (i * 4) & (H_ - 1);
    reinterpret_cast<float4*>(out)[i] = *reinterpret_cast<const float4*>(&cbias[h]);
  }
}

// ---------------- f32 -> bf16 conversion ----------------------------------
__global__ void cvt_f32_bf16(const float* __restrict__ in,
                             unsigned short* __restrict__ outp, int n4) {
  int stride = gridDim.x * blockDim.x;
  for (int i = blockIdx.x * blockDim.x + threadIdx.x; i < n4; i += stride) {
    float4 v = reinterpret_cast<const float4*>(in)[i];
    ushort4 o;
    o.x = f2bf(v.x); o.y = f2bf(v.y); o.z = f2bf(v.z); o.w = f2bf(v.w);
    reinterpret_cast<ushort4*>(outp)[i] = o;
  }
}

// ---------------- softmax + histogram -------------------------------------
__global__ void prep_kernel(const float* __restrict__ score,
                            const int* __restrict__ aidx,
                            float* __restrict__ w_buf,
                            int* __restrict__ counts) {
  __shared__ int hist[NB_];
  int tid = threadIdx.x;
  if (tid < NB_) hist[tid] = 0;
  __syncthreads();
  int n = blockIdx.x * 256 + tid;
  float s[K_];
  float m = -1e30f;
#pragma unroll
  for (int k = 0; k < K_; k++) { s[k] = score[n * K_ + k]; m = fmaxf(m, s[k]); }
  float sum = 0.f;
#pragma unroll
  for (int k = 0; k < K_; k++) { s[k] = __expf(s[k] - m); sum += s[k]; }
  float inv = 1.f / sum;
#pragma unroll
  for (int k = 0; k < K_; k++) {
    w_buf[n * K_ + k] = s[k] * inv;
    atomicAdd(&hist[aidx[n * K_ + k]], 1);
  }
  __syncthreads();
  if (tid < NB_) atomicAdd(&counts[tid], hist[tid]);
}

// ---------------- scan (44 entries, serial) -------------------------------
__global__ void scan_kernel(const int* __restrict__ counts,
                            int* __restrict__ offsets,
                            int* __restrict__ cursors) {
  if (threadIdx.x == 0) {
    int acc = 0;
    for (int b = 0; b < NB_; b++) {
      offsets[b] = acc;
      cursors[b] = acc;
      acc += counts[b];
    }
    offsets[NB_] = acc;
  }
}

// ---------------- fill grouped lists --------------------------------------
__global__ void fill_kernel(const int* __restrict__ aidx,
                            const float* __restrict__ w_buf,
                            int* __restrict__ cursors,
                            int* __restrict__ tok_list,
                            float* __restrict__ wt_list) {
  int n = blockIdx.x * 256 + threadIdx.x;
#pragma unroll
  for (int k = 0; k < K_; k++) {
    int b = aidx[n * K_ + k];
    int pos = atomicAdd(&cursors[b], 1);
    tok_list[pos] = n;
    wt_list[pos] = w_buf[n * K_ + k];
  }
}

// ---------------- latent = silu(x @ enc_w.T + enc_b) ----------------------
__global__ void latent_kernel(const unsigned short* __restrict__ xb,
                              const float* __restrict__ enc_w,
                              const float* __restrict__ enc_b,
                              float* __restrict__ lat) {
  int r = threadIdx.x & 63, tg = threadIdx.x >> 6;
  int n0 = blockIdx.x * 16 + tg * 4;
  float a0 = 0.f, a1 = 0.f, a2 = 0.f, a3 = 0.f;
  const float* er = enc_w + (size_t)r * H_;
  const unsigned short* x0 = xb + (size_t)(n0 + 0) * H_;
  const unsigned short* x1 = xb + (size_t)(n0 + 1) * H_;
  const unsigned short* x2 = xb + (size_t)(n0 + 2) * H_;
  const unsigned short* x3 = xb + (size_t)(n0 + 3) * H_;
  for (int h = 0; h < H_; h += 4) {
    float4 e = *reinterpret_cast<const float4*>(er + h);
    ushort4 u0 = *reinterpret_cast<const ushort4*>(x0 + h);
    ushort4 u1 = *reinterpret_cast<const ushort4*>(x1 + h);
    ushort4 u2 = *reinterpret_cast<const ushort4*>(x2 + h);
    ushort4 u3 = *reinterpret_cast<const ushort4*>(x3 + h);
    a0 += e.x * bf2f(u0.x) + e.y * bf2f(u0.y) + e.z * bf2f(u0.z) + e.w * bf2f(u0.w);
    a1 += e.x * bf2f(u1.x) + e.y * bf2f(u1.y) + e.z * bf2f(u1.z) + e.w * bf2f(u1.w);
    a2 += e.x * bf2f(u2.x) + e.y * bf2f(u2.y) + e.z * bf2f(u2.z) + e.w * bf2f(u2.w);
    a3 += e.x * bf2f(u3.x) + e.y * bf2f(u3.y) + e.z * bf2f(u3.z) + e.w * bf2f(u3.w);
  }
  float eb = enc_b[r];
  float v;
  v = a0 + eb; lat[(size_t)(n0 + 0) * R_ + r] = v / (1.f + __expf(-v));
  v = a1 + eb; lat[(size_t)(n0 + 1) * R_ + r] = v / (1.f + __expf(-v));
  v = a2 + eb; lat[(size_t)(n0 + 2) * R_ + r] = v / (1.f + __expf(-v));
  v = a3 + eb; lat[(size_t)(n0 + 3) * R_ + r] = v / (1.f + __expf(-v));
}

// ---------------- main grouped kernel -------------------------------------
__global__ __launch_bounds__(256) void main_kernel(
    const unsigned short* __restrict__ xb,
    const unsigned short* __restrict__ gwb,
    const unsigned short* __restrict__ uwb,
    const unsigned short* __restrict__ dwb,
    const float* __restrict__ latent,
    const float* __restrict__ decoder,
    const float* __restrict__ bbias,
    const float* __restrict__ scale_p,
    const int* __restrict__ counts,
    const int* __restrict__ offsets,
    const int* __restrict__ tok_list,
    const float* __restrict__ wt_list,
    float* __restrict__ out) {
  int b = blockIdx.x / TILES;
  int tile = blockIdx.x % TILES;
  int cnt = counts[b];
  int base = tile * MT;
  if (base >= cnt) return;
  int off = offsets[b];

  __shared__ int   tok_lds[MT];
  __shared__ float wt_lds[MT];
  __shared__ float lat_lds[MT][R_];
  __shared__ __align__(16) unsigned short a_lds[MT * BS_];

  int tid = threadIdx.x;
  if (tid < MT) {
    int g = base + tid;
    int tok = 0; float wt = 0.f;
    if (g < cnt) { tok = tok_list[off + g]; wt = wt_list[off + g]; }
    tok_lds[tid] = tok; wt_lds[tid] = wt;
  }
  __syncthreads();
  for (int idx = tid; idx < MT * R_; idx += 256) {
    int t = idx >> 6, r = idx & (R_ - 1);
    lat_lds[t][r] = latent[(size_t)tok_lds[t] * R_ + r];
  }

  int wv = tid >> 6;          // wave 0..3
  int lane = tid & 63;
  int lo = lane & 15, hi = lane >> 4;

  int tokA[4];
#pragma unroll
  for (int m = 0; m < 4; m++) tokA[m] = tok_lds[m * 16 + lo];
  __syncthreads();            // lat_lds ready (used in phase 2)

  const unsigned short* gb = gwb + (size_t)b * BS_ * H_;
  const unsigned short* ub = uwb + (size_t)b * BS_ * H_;
  const unsigned short* xr[4];
#pragma unroll
  for (int m = 0; m < 4; m++) xr[m] = xb + (size_t)tokA[m] * H_;
  int c0 = wv * 32 + lo;

  // ---------- phase 1: gate/up GEMM (M=64, N=32/wave, K=2048) ----------
  f32x4 accG[4][2] = {};
  f32x4 accU[4][2] = {};
  for (int ks = 0; ks < H_; ks += 32) {
    int ko = ks + hi * 8;
    bf16x8 A[4];
#pragma unroll
    for (int m = 0; m < 4; m++) A[m] = ld8(xr[m] + ko);
#pragma unroll
    for (int c2 = 0; c2 < 2; c2++) {
      size_t ro = (size_t)(c0 + c2 * 16) * H_ + ko;
      bf16x8 Bg = ld8(gb + ro);
      bf16x8 Bu = ld8(ub + ro);
#pragma unroll
      for (int m = 0; m < 4; m++) {
        accG[m][c2] = __builtin_amdgcn_mfma_f32_16x16x32_bf16(A[m], Bg, accG[m][c2], 0, 0, 0);
        accU[m][c2] = __builtin_amdgcn_mfma_f32_16x16x32_bf16(A[m], Bu, accU[m][c2], 0, 0, 0);
      }
    }
  }

  // ---------- phase 2: comp + silu + weight, transpose to LDS ----------
  float scal = scale_p[0];
  const float* decb = decoder + (size_t)b * R_ * BS_;
  int cA = c0, cB = c0 + 16;
  float comp[4][2][4] = {};
#pragma unroll 4
  for (int r2 = 0; r2 < R_; r2++) {
    float d0 = decb[r2 * BS_ + cA];
    float d1 = decb[r2 * BS_ + cB];
#pragma unroll
    for (int m = 0; m < 4; m++) {
#pragma unroll
      for (int r = 0; r < 4; r++) {
        float lv = lat_lds[m * 16 + hi * 4 + r][r2];
        comp[m][0][r] = fmaf(lv, d0, comp[m][0][r]);
        comp[m][1][r] = fmaf(lv, d1, comp[m][1][r]);
      }
    }
  }
  float bb[2] = { bbias[b * BS_ + cA], bbias[b * BS_ + cB] };
  float wtr[4][4];
#pragma unroll
  for (int m = 0; m < 4; m++)
#pragma unroll
    for (int r = 0; r < 4; r++) wtr[m][r] = wt_lds[m * 16 + hi * 4 + r];

#pragma unroll
  for (int m = 0; m < 4; m++) {
#pragma unroll
    for (int c2 = 0; c2 < 2; c2++) {
      int c = (c2 ? cB : cA);
      int cb = c >> 3;
#pragma unroll
      for (int r = 0; r < 4; r++) {
        int t = m * 16 + hi * 4 + r;
        float g = accG[m][c2][r];
        float u = accU[m][c2][r];
        float act = (g / (1.f + __expf(-g))) * u;
        float a = (act + scal * (comp[m][c2][r] + bb[c2])) * wtr[m][r];
        a_lds[t * BS_ + (((cb ^ (t & 7)) << 3) | (c & 7))] = f2bf(a);
      }
    }
  }
  __syncthreads();

  // ---------- phase 3: down GEMM (M=64, K=128, N=2048) + scatter -------
  int tokP[4][4];
#pragma unroll
  for (int m = 0; m < 4; m++)
#pragma unroll
    for (int r = 0; r < 4; r++) tokP[m][r] = tok_lds[m * 16 + hi * 4 + r];

  const unsigned short* db = dwb + (size_t)b * BS_;
  for (int hc = 0; hc < 8; hc++) {
    f32x4 acc2[4][4] = {};
#pragma unroll
    for (int kst = 0; kst < 4; kst++) {
      bf16x8 A2[4];
#pragma unroll
      for (int m = 0; m < 4; m++) {
        int t = m * 16 + lo;
        int cb = kst * 4 + hi;
        A2[m] = ld8(&a_lds[t * BS_ + ((cb ^ (t & 7)) << 3)]);
      }
#pragma unroll
      for (int c4 = 0; c4 < 4; c4++) {
        int h = hc * 256 + wv * 64 + c4 * 16 + lo;
        bf16x8 B2 = ld8(db + (size_t)h * I_ + kst * 32 + hi * 8);
#pragma unroll
        for (int m = 0; m < 4; m++)
          acc2[m][c4] = __builtin_amdgcn_mfma_f32_16x16x32_bf16(A2[m], B2, acc2[m][c4], 0, 0, 0);
      }
    }
#pragma unroll
    for (int m = 0; m < 4; m++) {
#pragma unroll
      for (int c4 = 0; c4 < 4; c4++) {
        int h = hc * 256 + wv * 64 + c4 * 16 + lo;
#pragma unroll
        for (int r = 0; r < 4; r++)
          atomicAdd(&out[(size_t)tokP[m][r] * H_ + h], acc2[m][c4][r]);
      }
    }
  }
}

// ---------------- launch ---------------------------------------------------
extern "C" void kernel_launch(void* const* d_in, const int* in_sizes, int n_in,
                              void* d_out, int out_size, void* d_ws, size_t ws_size,
                              hipStream_t stream) {
  const float* x       = (const float*)d_in[0];
  const int*   aidx    = (const int*)d_in[1];
  const float* score   = (const float*)d_in[2];
  const float* gate_w  = (const float*)d_in[3];
  const float* up_w    = (const float*)d_in[4];
  const float* down_w  = (const float*)d_in[5];
  const float* enc_w   = (const float*)d_in[6];
  const float* enc_b   = (const float*)d_in[7];
  const float* decoder = (const float*)d_in[8];
  const float* bbias   = (const float*)d_in[9];
  const float* cbias   = (const float*)d_in[10];
  const float* scale   = (const float*)d_in[11];
  float* out = (float*)d_out;

  char* ws = (char*)d_ws;
  unsigned short* xb  = (unsigned short*)(ws + 0);
  unsigned short* gwb = (unsigned short*)(ws + 33554432ull);
  unsigned short* uwb = (unsigned short*)(ws + 56623104ull);
  unsigned short* dwb = (unsigned short*)(ws + 79691776ull);
  float* lat          = (float*)(ws + 102760448ull);
  float* w_buf        = (float*)(ws + 104857600ull);
  int*   tok_list     = (int*)(ws + 105119744ull);
  float* wt_list      = (float*)(ws + 105381888ull);
  int*   counts       = (int*)(ws + 105644032ull);
  int*   offsets      = counts + 64;
  int*   cursors      = counts + 128;

  init_out_kernel<<<2048, 256, 0, stream>>>(out, cbias, counts);
  cvt_f32_bf16<<<1024, 256, 0, stream>>>(x, xb, N_ * H_ / 4);
  cvt_f32_bf16<<<1024, 256, 0, stream>>>(gate_w, gwb, I_ * H_ / 4);
  cvt_f32_bf16<<<1024, 256, 0, stream>>>(up_w, uwb, I_ * H_ / 4);
  cvt_f32_bf16<<<1024, 256, 0, stream>>>(down_w, dwb, H_ * I_ / 4);
  prep_kernel<<<N_ / 256, 256, 0, stream>>>(score, aidx, w_buf, counts);
  scan_kernel<<<1, 64, 0, stream>>>(counts, offsets, cursors);
  fill_kernel<<<N_ / 256, 256, 0, stream>>>(aidx, w_buf, cursors, tok_list, wt_list);
  latent_kernel<<<N_ / 16, 256, 0, stream>>>(xb, enc_w, enc_b, lat);
  main_kernel<<<NB_ * TILES, 256, 0, stream>>>(xb, gwb, uwb, dwb, lat, decoder, bbias,
                                               scale, counts, offsets, tok_list, wt_list, out);
}

// Round 2
// 899.746 us; speedup vs baseline: 1.6734x; 1.6734x over previous
//
#include <hip/hip_runtime.h>

#define H_  2048
#define BS_ 128
#define NB_ 44
#define R_  64
#define K_  8
#define N_  8192
#define I_  5632
#define MT  64
#define TILES 32
#define NSLOT (N_*K_)          // 65536 (all idx valid)
#define GRID_AB (8 * 6 * TILES)  // XCD-pinned decode covers b in [0,48)

typedef __bf16 bf16x8 __attribute__((ext_vector_type(8)));
typedef float  f32x4  __attribute__((ext_vector_type(4)));

__device__ __forceinline__ unsigned short f2bf(float f) {
  unsigned int u = __float_as_uint(f);
  u = (u + 0x7FFFu + ((u >> 16) & 1u)) >> 16;   // RNE, inputs finite
  return (unsigned short)u;
}
__device__ __forceinline__ float bf2f(unsigned short s) {
  return __uint_as_float(((unsigned int)s) << 16);
}
__device__ __forceinline__ bf16x8 ld8(const unsigned short* p) {
  uint4 v = *reinterpret_cast<const uint4*>(p);
  return __builtin_bit_cast(bf16x8, v);
}

// ---------------- conversions ---------------------------------------------
__global__ void cvt_xgu(const float* __restrict__ x, const float* __restrict__ gw,
                        const float* __restrict__ uw,
                        unsigned short* __restrict__ xb,
                        unsigned short* __restrict__ gwb,
                        unsigned short* __restrict__ uwb) {
  const int NX4 = N_ * H_ / 4;
  const int NG4 = I_ * H_ / 4;
  int total = NX4 + 2 * NG4;
  int stride = gridDim.x * blockDim.x;
  for (int i = blockIdx.x * blockDim.x + threadIdx.x; i < total; i += stride) {
    const float4* s; ushort4* d; int j;
    if (i < NX4)            { s = (const float4*)x;  d = (ushort4*)xb;  j = i; }
    else if (i < NX4 + NG4) { s = (const float4*)gw; d = (ushort4*)gwb; j = i - NX4; }
    else                    { s = (const float4*)uw; d = (ushort4*)uwb; j = i - NX4 - NG4; }
    float4 v = s[j];
    ushort4 o; o.x = f2bf(v.x); o.y = f2bf(v.y); o.z = f2bf(v.z); o.w = f2bf(v.w);
    d[j] = o;
  }
}

// down_w [H][I] f32 -> dwb [NB][H][128] bf16 (block-major)
__global__ void cvt_down(const float* __restrict__ dw, unsigned short* __restrict__ dwb) {
  int total = H_ * I_ / 4;
  int stride = gridDim.x * blockDim.x;
  for (int i = blockIdx.x * blockDim.x + threadIdx.x; i < total; i += stride) {
    float4 v = ((const float4*)dw)[i];
    int flat = i * 4;
    int h = flat / I_;
    int rem = flat - h * I_;
    int b = rem >> 7, k = rem & 127;
    ushort4 o; o.x = f2bf(v.x); o.y = f2bf(v.y); o.z = f2bf(v.z); o.w = f2bf(v.w);
    *(ushort4*)(dwb + ((size_t)b * H_ + h) * BS_ + k) = o;
  }
}

// ---------------- routing prep --------------------------------------------
__global__ void zero_counts(int* __restrict__ counts) {
  if (threadIdx.x < NB_) counts[threadIdx.x] = 0;
}

__global__ void prep_kernel(const float* __restrict__ score,
                            const int* __restrict__ aidx,
                            float* __restrict__ w_buf,
                            int* __restrict__ counts) {
  __shared__ int hist[NB_];
  int tid = threadIdx.x;
  if (tid < NB_) hist[tid] = 0;
  __syncthreads();
  int n = blockIdx.x * 256 + tid;
  float s[K_];
  float m = -1e30f;
#pragma unroll
  for (int k = 0; k < K_; k++) { s[k] = score[n * K_ + k]; m = fmaxf(m, s[k]); }
  float sum = 0.f;
#pragma unroll
  for (int k = 0; k < K_; k++) { s[k] = __expf(s[k] - m); sum += s[k]; }
  float inv = 1.f / sum;
#pragma unroll
  for (int k = 0; k < K_; k++) {
    w_buf[n * K_ + k] = s[k] * inv;
    atomicAdd(&hist[aidx[n * K_ + k]], 1);
  }
  __syncthreads();
  if (tid < NB_) atomicAdd(&counts[tid], hist[tid]);
}

__global__ void scan_kernel(const int* __restrict__ counts,
                            int* __restrict__ offsets,
                            int* __restrict__ cursors) {
  if (threadIdx.x == 0) {
    int acc = 0;
    for (int b = 0; b < NB_; b++) { offsets[b] = acc; cursors[b] = acc; acc += counts[b]; }
    offsets[NB_] = acc;
  }
}

__global__ void fill_kernel(const int* __restrict__ aidx,
                            const float* __restrict__ w_buf,
                            int* __restrict__ cursors,
                            int* __restrict__ tok_list,
                            float* __restrict__ wt_list,
                            int* __restrict__ inv) {
  int n = blockIdx.x * 256 + threadIdx.x;
#pragma unroll
  for (int k = 0; k < K_; k++) {
    int b = aidx[n * K_ + k];
    int pos = atomicAdd(&cursors[b], 1);
    tok_list[pos] = n;
    wt_list[pos] = w_buf[n * K_ + k];
    inv[n * K_ + k] = pos;
  }
}

// ---------------- latent = silu(x @ enc_w.T + enc_b) ----------------------
__global__ void latent_kernel(const unsigned short* __restrict__ xb,
                              const float* __restrict__ enc_w,
                              const float* __restrict__ enc_b,
                              float* __restrict__ lat) {
  int r = threadIdx.x & 63, tg = threadIdx.x >> 6;
  int n0 = blockIdx.x * 16 + tg * 4;
  float a0 = 0.f, a1 = 0.f, a2 = 0.f, a3 = 0.f;
  const float* er = enc_w + (size_t)r * H_;
  const unsigned short* x0 = xb + (size_t)(n0 + 0) * H_;
  const unsigned short* x1 = xb + (size_t)(n0 + 1) * H_;
  const unsigned short* x2 = xb + (size_t)(n0 + 2) * H_;
  const unsigned short* x3 = xb + (size_t)(n0 + 3) * H_;
  for (int h = 0; h < H_; h += 4) {
    float4 e = *reinterpret_cast<const float4*>(er + h);
    ushort4 u0 = *reinterpret_cast<const ushort4*>(x0 + h);
    ushort4 u1 = *reinterpret_cast<const ushort4*>(x1 + h);
    ushort4 u2 = *reinterpret_cast<const ushort4*>(x2 + h);
    ushort4 u3 = *reinterpret_cast<const ushort4*>(x3 + h);
    a0 += e.x * bf2f(u0.x) + e.y * bf2f(u0.y) + e.z * bf2f(u0.z) + e.w * bf2f(u0.w);
    a1 += e.x * bf2f(u1.x) + e.y * bf2f(u1.y) + e.z * bf2f(u1.z) + e.w * bf2f(u1.w);
    a2 += e.x * bf2f(u2.x) + e.y * bf2f(u2.y) + e.z * bf2f(u2.z) + e.w * bf2f(u2.w);
    a3 += e.x * bf2f(u3.x) + e.y * bf2f(u3.y) + e.z * bf2f(u3.z) + e.w * bf2f(u3.w);
  }
  float eb = enc_b[r];
  float v;
  v = a0 + eb; lat[(size_t)(n0 + 0) * R_ + r] = v / (1.f + __expf(-v));
  v = a1 + eb; lat[(size_t)(n0 + 1) * R_ + r] = v / (1.f + __expf(-v));
  v = a2 + eb; lat[(size_t)(n0 + 2) * R_ + r] = v / (1.f + __expf(-v));
  v = a3 + eb; lat[(size_t)(n0 + 3) * R_ + r] = v / (1.f + __expf(-v));
}

// XCD-pinned decode: all tiles of block b land on XCD b%8
__device__ __forceinline__ bool decode_bt(int p, int& b, int& tile) {
  b = (p & 7) + 8 * ((p >> 3) / TILES);
  tile = (p >> 3) % TILES;
  return b < NB_;
}

// ---------------- gate/up kernel: writes weighted activations per slot ----
__global__ __launch_bounds__(256) void gateup_kernel(
    const unsigned short* __restrict__ xb,
    const unsigned short* __restrict__ gwb,
    const unsigned short* __restrict__ uwb,
    const float* __restrict__ latent,
    const float* __restrict__ decoder,
    const float* __restrict__ bbias,
    const float* __restrict__ scale_p,
    const int* __restrict__ counts,
    const int* __restrict__ offsets,
    const int* __restrict__ tok_list,
    const float* __restrict__ wt_list,
    unsigned short* __restrict__ actw) {
  int b, tile;
  if (!decode_bt(blockIdx.x, b, tile)) return;
  int cnt = counts[b];
  int base = tile * MT;
  if (base >= cnt) return;
  int off = offsets[b];

  __shared__ int   tok_lds[MT];
  __shared__ float wt_lds[MT];
  __shared__ float lat_lds[MT][R_ + 1];   // +1 pad: kills 16-way column conflicts

  int tid = threadIdx.x;
  if (tid < MT) {
    int g = base + tid;
    int tok = 0; float wt = 0.f;
    if (g < cnt) { tok = tok_list[off + g]; wt = wt_list[off + g]; }
    tok_lds[tid] = tok; wt_lds[tid] = wt;
  }
  __syncthreads();
  for (int idx = tid; idx < MT * R_; idx += 256) {
    int t = idx >> 6, r = idx & (R_ - 1);
    lat_lds[t][r] = latent[(size_t)tok_lds[t] * R_ + r];
  }

  int wv = tid >> 6;
  int lane = tid & 63;
  int lo = lane & 15, hi = lane >> 4;

  int tokA[4];
#pragma unroll
  for (int m = 0; m < 4; m++) tokA[m] = tok_lds[m * 16 + lo];
  __syncthreads();

  const unsigned short* gb = gwb + (size_t)b * BS_ * H_;
  const unsigned short* ub = uwb + (size_t)b * BS_ * H_;
  const unsigned short* xr[4];
#pragma unroll
  for (int m = 0; m < 4; m++) xr[m] = xb + (size_t)tokA[m] * H_;
  int c0 = wv * 32 + lo;

  // gate/up GEMM (M=64, N=32/wave, K=2048)
  f32x4 accG[4][2] = {};
  f32x4 accU[4][2] = {};
  for (int ks = 0; ks < H_; ks += 32) {
    int ko = ks + hi * 8;
    bf16x8 A[4];
#pragma unroll
    for (int m = 0; m < 4; m++) A[m] = ld8(xr[m] + ko);
#pragma unroll
    for (int c2 = 0; c2 < 2; c2++) {
      size_t ro = (size_t)(c0 + c2 * 16) * H_ + ko;
      bf16x8 Bg = ld8(gb + ro);
      bf16x8 Bu = ld8(ub + ro);
#pragma unroll
      for (int m = 0; m < 4; m++) {
        accG[m][c2] = __builtin_amdgcn_mfma_f32_16x16x32_bf16(A[m], Bg, accG[m][c2], 0, 0, 0);
        accU[m][c2] = __builtin_amdgcn_mfma_f32_16x16x32_bf16(A[m], Bu, accU[m][c2], 0, 0, 0);
      }
    }
  }

  // epilogue: comp + silu + routing weight -> actw[slot][c]
  float scal = scale_p[0];
  const float* decb = decoder + (size_t)b * R_ * BS_;
  int cA = c0, cB = c0 + 16;
  float comp[4][2][4] = {};
#pragma unroll 4
  for (int r2 = 0; r2 < R_; r2++) {
    float d0 = decb[r2 * BS_ + cA];
    float d1 = decb[r2 * BS_ + cB];
#pragma unroll
    for (int m = 0; m < 4; m++) {
#pragma unroll
      for (int r = 0; r < 4; r++) {
        float lv = lat_lds[m * 16 + hi * 4 + r][r2];
        comp[m][0][r] = fmaf(lv, d0, comp[m][0][r]);
        comp[m][1][r] = fmaf(lv, d1, comp[m][1][r]);
      }
    }
  }
  float bb[2] = { bbias[b * BS_ + cA], bbias[b * BS_ + cB] };

#pragma unroll
  for (int m = 0; m < 4; m++) {
#pragma unroll
    for (int r = 0; r < 4; r++) {
      int t = m * 16 + hi * 4 + r;
      int g = base + t;
      if (g < cnt) {
        float wt = wt_lds[t];
        unsigned short* dst = actw + (size_t)(off + g) * BS_;
#pragma unroll
        for (int c2 = 0; c2 < 2; c2++) {
          int c = (c2 ? cB : cA);
          float gg = accG[m][c2][r];
          float uu = accU[m][c2][r];
          float act = (gg / (1.f + __expf(-gg))) * uu;
          dst[c] = f2bf((act + scal * (comp[m][c2][r] + bb[c2])) * wt);
        }
      }
    }
  }
}

// ---------------- down kernel: partial[slot][h-chunk] = actw @ down_b -----
__global__ __launch_bounds__(256) void down_kernel(
    const unsigned short* __restrict__ actw,
    const unsigned short* __restrict__ dwb,
    const int* __restrict__ counts,
    const int* __restrict__ offsets,
    unsigned short* __restrict__ partial,
    int hc0, int Hc) {
  int b, tile;
  if (!decode_bt(blockIdx.x, b, tile)) return;
  int cnt = counts[b];
  int base = tile * MT;
  if (base >= cnt) return;
  int off = offsets[b];

  __shared__ __align__(16) unsigned short a_lds[MT * BS_];
  int tid = threadIdx.x;
  // stage A-tile (64 slots x 128 ch), XOR-swizzled
  for (int i = tid; i < MT * BS_ / 8; i += 256) {
    int t = i >> 4, cb = i & 15;
    int g = base + t;
    uint4 v = make_uint4(0, 0, 0, 0);
    if (g < cnt) v = *(const uint4*)(actw + (size_t)(off + g) * BS_ + cb * 8);
    *(uint4*)(&a_lds[t * BS_ + ((cb ^ (t & 7)) << 3)]) = v;
  }
  __syncthreads();

  int wv = tid >> 6, lane = tid & 63;
  int lo = lane & 15, hi = lane >> 4;
  const unsigned short* db = dwb + (size_t)b * H_ * BS_;

  for (int h0 = wv * 64; h0 < Hc; h0 += 256) {
    f32x4 acc[4][4] = {};
#pragma unroll
    for (int kst = 0; kst < 4; kst++) {
      bf16x8 A2[4];
#pragma unroll
      for (int m = 0; m < 4; m++) {
        int t = m * 16 + lo, cb = kst * 4 + hi;
        A2[m] = ld8(&a_lds[t * BS_ + ((cb ^ (t & 7)) << 3)]);
      }
#pragma unroll
      for (int c4 = 0; c4 < 4; c4++) {
        int h = hc0 + h0 + c4 * 16 + lo;
        bf16x8 B2 = ld8(db + (size_t)h * BS_ + kst * 32 + hi * 8);
#pragma unroll
        for (int m = 0; m < 4; m++)
          acc[m][c4] = __builtin_amdgcn_mfma_f32_16x16x32_bf16(A2[m], B2, acc[m][c4], 0, 0, 0);
      }
    }
#pragma unroll
    for (int m = 0; m < 4; m++) {
#pragma unroll
      for (int r = 0; r < 4; r++) {
        int g = base + m * 16 + hi * 4 + r;
        if (g < cnt) {
          unsigned short* pr = partial + (size_t)(off + g) * Hc + h0;
#pragma unroll
          for (int c4 = 0; c4 < 4; c4++) pr[c4 * 16 + lo] = f2bf(acc[m][c4][r]);
        }
      }
    }
  }
}

// ---------------- reduce: out[n][h] = cbias[h] + sum_k partial[inv[n,k]][h]
__global__ __launch_bounds__(256) void reduce_kernel(
    const unsigned short* __restrict__ partial,
    const int* __restrict__ inv,
    const float* __restrict__ cbias,
    float* __restrict__ out, int hc0, int Hc) {
  int wv = threadIdx.x >> 6, l = threadIdx.x & 63;
  int n = blockIdx.x * 4 + wv;
  int rows[K_];
#pragma unroll
  for (int k = 0; k < K_; k++) rows[k] = inv[n * K_ + k];
  for (int c0w = 0; c0w < Hc; c0w += 512) {
    int cw = c0w + l * 8;
    if (cw >= Hc) continue;
    float a[8] = {0.f, 0.f, 0.f, 0.f, 0.f, 0.f, 0.f, 0.f};
#pragma unroll
    for (int k = 0; k < K_; k++) {
      uint4 v = *(const uint4*)(partial + (size_t)rows[k] * Hc + cw);
      unsigned int w0 = v.x, w1 = v.y, w2 = v.z, w3 = v.w;
      a[0] += __uint_as_float(w0 << 16); a[1] += __uint_as_float(w0 & 0xFFFF0000u);
      a[2] += __uint_as_float(w1 << 16); a[3] += __uint_as_float(w1 & 0xFFFF0000u);
      a[4] += __uint_as_float(w2 << 16); a[5] += __uint_as_float(w2 & 0xFFFF0000u);
      a[6] += __uint_as_float(w3 << 16); a[7] += __uint_as_float(w3 & 0xFFFF0000u);
    }
    int h = hc0 + cw;
    float4 c0 = *(const float4*)(cbias + h);
    float4 c1 = *(const float4*)(cbias + h + 4);
    float4 o0 = make_float4(a[0] + c0.x, a[1] + c0.y, a[2] + c0.z, a[3] + c0.w);
    float4 o1 = make_float4(a[4] + c1.x, a[5] + c1.y, a[6] + c1.z, a[7] + c1.w);
    *(float4*)(out + (size_t)n * H_ + h) = o0;
    *(float4*)(out + (size_t)n * H_ + h + 4) = o1;
  }
}

// ---------------- launch ---------------------------------------------------
extern "C" void kernel_launch(void* const* d_in, const int* in_sizes, int n_in,
                              void* d_out, int out_size, void* d_ws, size_t ws_size,
                              hipStream_t stream) {
  const float* x       = (const float*)d_in[0];
  const int*   aidx    = (const int*)d_in[1];
  const float* score   = (const float*)d_in[2];
  const float* gate_w  = (const float*)d_in[3];
  const float* up_w    = (const float*)d_in[4];
  const float* down_w  = (const float*)d_in[5];
  const float* enc_w   = (const float*)d_in[6];
  const float* enc_b   = (const float*)d_in[7];
  const float* decoder = (const float*)d_in[8];
  const float* bbias   = (const float*)d_in[9];
  const float* cbias   = (const float*)d_in[10];
  const float* scale   = (const float*)d_in[11];
  float* out = (float*)d_out;

  char* ws = (char*)d_ws;
  const size_t OFF_GWB  = 33554432ull;
  const size_t OFF_UWB  = 56623104ull;
  const size_t OFF_LAT  = 79691776ull;
  const size_t OFF_WBUF = 81788928ull;
  const size_t OFF_TOK  = 82051072ull;
  const size_t OFF_WT   = 82313216ull;
  const size_t OFF_INV  = 82575360ull;
  const size_t OFF_CNT  = 82837504ull;
  const size_t OFF_ACTW = 82838528ull;
  const size_t BASE_END = 99615744ull;
  const size_t DWB_SZ   = 23068672ull;

  unsigned short* xb   = (unsigned short*)(ws);
  unsigned short* gwb  = (unsigned short*)(ws + OFF_GWB);
  unsigned short* uwb  = (unsigned short*)(ws + OFF_UWB);
  float* lat           = (float*)(ws + OFF_LAT);
  float* w_buf         = (float*)(ws + OFF_WBUF);
  int*   tok_list      = (int*)(ws + OFF_TOK);
  float* wt_list       = (float*)(ws + OFF_WT);
  int*   inv           = (int*)(ws + OFF_INV);
  int*   counts        = (int*)(ws + OFF_CNT);
  int*   offsets       = counts + 64;
  int*   cursors       = counts + 128;
  unsigned short* actw = (unsigned short*)(ws + OFF_ACTW);

  // adaptive partial-buffer placement
  int Hc; unsigned short* dwb; unsigned short* partial; bool early_down;
  if      (ws_size >= BASE_END + DWB_SZ + 131072ull * 2048) Hc = 2048;
  else if (ws_size >= BASE_END + DWB_SZ + 131072ull * 1024) Hc = 1024;
  else if (ws_size >= BASE_END + DWB_SZ + 131072ull * 512)  Hc = 512;
  else if (ws_size >= BASE_END + DWB_SZ + 131072ull * 256)  Hc = 256;
  else Hc = 0;
  if (Hc) {
    early_down = true;
    dwb = (unsigned short*)(ws + BASE_END);
    partial = (unsigned short*)(ws + BASE_END + DWB_SZ);
  } else {
    early_down = false;      // squeeze: dwb reuses gate region, partial reuses x region
    Hc = 256;
    dwb = gwb;
    partial = (unsigned short*)ws;
  }
  int nch = H_ / Hc;

  cvt_xgu<<<2048, 256, 0, stream>>>(x, gate_w, up_w, xb, gwb, uwb);
  if (early_down) cvt_down<<<2048, 256, 0, stream>>>(down_w, dwb);
  zero_counts<<<1, 64, 0, stream>>>(counts);
  prep_kernel<<<N_ / 256, 256, 0, stream>>>(score, aidx, w_buf, counts);
  scan_kernel<<<1, 64, 0, stream>>>(counts, offsets, cursors);
  fill_kernel<<<N_ / 256, 256, 0, stream>>>(aidx, w_buf, cursors, tok_list, wt_list, inv);
  latent_kernel<<<N_ / 16, 256, 0, stream>>>(xb, enc_w, enc_b, lat);
  gateup_kernel<<<GRID_AB, 256, 0, stream>>>(xb, gwb, uwb, lat, decoder, bbias, scale,
                                             counts, offsets, tok_list, wt_list, actw);
  if (!early_down) cvt_down<<<2048, 256, 0, stream>>>(down_w, dwb);
  for (int c = 0; c < nch; c++) {
    down_kernel<<<GRID_AB, 256, 0, stream>>>(actw, dwb, counts, offsets, partial, c * Hc, Hc);
    reduce_kernel<<<N_ / 4, 256, 0, stream>>>(partial, inv, cbias, out, c * Hc, Hc);
  }
}

// Round 3
// 839.074 us; speedup vs baseline: 1.7944x; 1.0723x over previous
//
#include <hip/hip_runtime.h>

#define H_  2048
#define BS_ 128
#define NB_ 44
#define R_  64
#define K_  8
#define N_  8192
#define I_  5632
#define MT  64
#define TILES 32
#define GRID_AB (8 * 6 * TILES)

typedef __bf16 bf16x8 __attribute__((ext_vector_type(8)));
typedef float  f32x4  __attribute__((ext_vector_type(4)));

__device__ __forceinline__ unsigned short f2bf(float f) {
  unsigned int u = __float_as_uint(f);
  u = (u + 0x7FFFu + ((u >> 16) & 1u)) >> 16;
  return (unsigned short)u;
}
__device__ __forceinline__ float bf2f(unsigned short s) {
  return __uint_as_float(((unsigned int)s) << 16);
}
__device__ __forceinline__ bf16x8 ld8(const unsigned short* p) {
  uint4 v = *reinterpret_cast<const uint4*>(p);
  return __builtin_bit_cast(bf16x8, v);
}
__device__ __forceinline__ bf16x8 lds8(const char* p) {
  uint4 v = *reinterpret_cast<const uint4*>(p);
  return __builtin_bit_cast(bf16x8, v);
}
// async global->LDS, 16B per lane; l must be wave-uniform base (HW adds lane*16)
__device__ __forceinline__ void gl16(const void* g, void* l) {
  __builtin_amdgcn_global_load_lds(
      (const __attribute__((address_space(1))) char*)g,
      (__attribute__((address_space(3))) char*)l, 16, 0, 0);
}

// ---------------- conversions ---------------------------------------------
__global__ void cvt_xgu(const float* __restrict__ x, const float* __restrict__ gw,
                        const float* __restrict__ uw,
                        unsigned short* __restrict__ xb,
                        unsigned short* __restrict__ gwb,
                        unsigned short* __restrict__ uwb) {
  const int NX4 = N_ * H_ / 4;
  const int NG4 = I_ * H_ / 4;
  int total = NX4 + 2 * NG4;
  int stride = gridDim.x * blockDim.x;
  for (int i = blockIdx.x * blockDim.x + threadIdx.x; i < total; i += stride) {
    const float4* s; ushort4* d; int j;
    if (i < NX4)            { s = (const float4*)x;  d = (ushort4*)xb;  j = i; }
    else if (i < NX4 + NG4) { s = (const float4*)gw; d = (ushort4*)gwb; j = i - NX4; }
    else                    { s = (const float4*)uw; d = (ushort4*)uwb; j = i - NX4 - NG4; }
    float4 v = s[j];
    ushort4 o; o.x = f2bf(v.x); o.y = f2bf(v.y); o.z = f2bf(v.z); o.w = f2bf(v.w);
    d[j] = o;
  }
}

// down_w [H][I] f32 -> dwb [NB][H][128] bf16
__global__ void cvt_down(const float* __restrict__ dw, unsigned short* __restrict__ dwb) {
  int total = H_ * I_ / 4;
  int stride = gridDim.x * blockDim.x;
  for (int i = blockIdx.x * blockDim.x + threadIdx.x; i < total; i += stride) {
    float4 v = ((const float4*)dw)[i];
    int flat = i * 4;
    int h = flat / I_;
    int rem = flat - h * I_;
    int b = rem >> 7, k = rem & 127;
    ushort4 o; o.x = f2bf(v.x); o.y = f2bf(v.y); o.z = f2bf(v.z); o.w = f2bf(v.w);
    *(ushort4*)(dwb + ((size_t)b * H_ + h) * BS_ + k) = o;
  }
}

// decoder [NB][R][BS] f32 -> dec_bf [NB][BS][R] bf16 (transposed)
__global__ void cvt_dec(const float* __restrict__ dec, unsigned short* __restrict__ decb) {
  int i = blockIdx.x * 256 + threadIdx.x;
  if (i >= NB_ * BS_ * R_) return;
  int b = i >> 13;
  int rem = i & 8191;
  int c = rem >> 6, r = rem & 63;
  decb[i] = f2bf(dec[(b << 13) + r * BS_ + c]);
}

// ---------------- routing prep --------------------------------------------
__global__ void zero_counts(int* __restrict__ counts) {
  if (threadIdx.x < NB_) counts[threadIdx.x] = 0;
}

__global__ void prep_kernel(const float* __restrict__ score,
                            const int* __restrict__ aidx,
                            float* __restrict__ w_buf,
                            int* __restrict__ counts) {
  __shared__ int hist[NB_];
  int tid = threadIdx.x;
  if (tid < NB_) hist[tid] = 0;
  __syncthreads();
  int n = blockIdx.x * 256 + tid;
  float s[K_];
  float m = -1e30f;
#pragma unroll
  for (int k = 0; k < K_; k++) { s[k] = score[n * K_ + k]; m = fmaxf(m, s[k]); }
  float sum = 0.f;
#pragma unroll
  for (int k = 0; k < K_; k++) { s[k] = __expf(s[k] - m); sum += s[k]; }
  float inv = 1.f / sum;
#pragma unroll
  for (int k = 0; k < K_; k++) {
    w_buf[n * K_ + k] = s[k] * inv;
    atomicAdd(&hist[aidx[n * K_ + k]], 1);
  }
  __syncthreads();
  if (tid < NB_) atomicAdd(&counts[tid], hist[tid]);
}

__global__ void scan_kernel(const int* __restrict__ counts,
                            int* __restrict__ offsets,
                            int* __restrict__ cursors) {
  if (threadIdx.x == 0) {
    int acc = 0;
    for (int b = 0; b < NB_; b++) { offsets[b] = acc; cursors[b] = acc; acc += counts[b]; }
    offsets[NB_] = acc;
  }
}

__global__ void fill_kernel(const int* __restrict__ aidx,
                            const float* __restrict__ w_buf,
                            int* __restrict__ cursors,
                            int* __restrict__ tok_list,
                            float* __restrict__ wt_list,
                            int* __restrict__ inv) {
  int n = blockIdx.x * 256 + threadIdx.x;
#pragma unroll
  for (int k = 0; k < K_; k++) {
    int b = aidx[n * K_ + k];
    int pos = atomicAdd(&cursors[b], 1);
    tok_list[pos] = n;
    wt_list[pos] = w_buf[n * K_ + k];
    inv[n * K_ + k] = pos;
  }
}

// ---------------- latent (bf16 out) ---------------------------------------
__global__ void latent_kernel(const unsigned short* __restrict__ xb,
                              const float* __restrict__ enc_w,
                              const float* __restrict__ enc_b,
                              unsigned short* __restrict__ lat) {
  int r = threadIdx.x & 63, tg = threadIdx.x >> 6;
  int n0 = blockIdx.x * 16 + tg * 4;
  float a0 = 0.f, a1 = 0.f, a2 = 0.f, a3 = 0.f;
  const float* er = enc_w + (size_t)r * H_;
  const unsigned short* x0 = xb + (size_t)(n0 + 0) * H_;
  const unsigned short* x1 = xb + (size_t)(n0 + 1) * H_;
  const unsigned short* x2 = xb + (size_t)(n0 + 2) * H_;
  const unsigned short* x3 = xb + (size_t)(n0 + 3) * H_;
  for (int h = 0; h < H_; h += 4) {
    float4 e = *reinterpret_cast<const float4*>(er + h);
    ushort4 u0 = *reinterpret_cast<const ushort4*>(x0 + h);
    ushort4 u1 = *reinterpret_cast<const ushort4*>(x1 + h);
    ushort4 u2 = *reinterpret_cast<const ushort4*>(x2 + h);
    ushort4 u3 = *reinterpret_cast<const ushort4*>(x3 + h);
    a0 += e.x * bf2f(u0.x) + e.y * bf2f(u0.y) + e.z * bf2f(u0.z) + e.w * bf2f(u0.w);
    a1 += e.x * bf2f(u1.x) + e.y * bf2f(u1.y) + e.z * bf2f(u1.z) + e.w * bf2f(u1.w);
    a2 += e.x * bf2f(u2.x) + e.y * bf2f(u2.y) + e.z * bf2f(u2.z) + e.w * bf2f(u2.w);
    a3 += e.x * bf2f(u3.x) + e.y * bf2f(u3.y) + e.z * bf2f(u3.z) + e.w * bf2f(u3.w);
  }
  float eb = enc_b[r];
  float v;
  v = a0 + eb; lat[(size_t)(n0 + 0) * R_ + r] = f2bf(v / (1.f + __expf(-v)));
  v = a1 + eb; lat[(size_t)(n0 + 1) * R_ + r] = f2bf(v / (1.f + __expf(-v)));
  v = a2 + eb; lat[(size_t)(n0 + 2) * R_ + r] = f2bf(v / (1.f + __expf(-v)));
  v = a3 + eb; lat[(size_t)(n0 + 3) * R_ + r] = f2bf(v / (1.f + __expf(-v)));
}

__device__ __forceinline__ bool decode_bt(int p, int& b, int& tile) {
  b = (p & 7) + 8 * ((p >> 3) / TILES);
  tile = (p >> 3) % TILES;
  return b < NB_;
}

// ---------------- gateup: pipelined LDS GEMM + MFMA comp ------------------
// LDS: A dbuf 2x4KB @0, Bg dbuf 2x8KB @8192, Bu dbuf 2x8KB @24576 (40KB)
// post-loop: dec 16KB reuses @8192, lat 8KB reuses @24576
__global__ __launch_bounds__(256, 3) void gateup_kernel(
    const unsigned short* __restrict__ xb,
    const unsigned short* __restrict__ gwb,
    const unsigned short* __restrict__ uwb,
    const unsigned short* __restrict__ latb,
    const unsigned short* __restrict__ decb_all,
    const float* __restrict__ bbias,
    const float* __restrict__ scale_p,
    const int* __restrict__ counts,
    const int* __restrict__ offsets,
    const int* __restrict__ tok_list,
    const float* __restrict__ wt_list,
    unsigned short* __restrict__ actw) {
  int b, tile;
  if (!decode_bt(blockIdx.x, b, tile)) return;
  int cnt = counts[b];
  int base = tile * MT;
  if (base >= cnt) return;
  int off = offsets[b];

  __shared__ __align__(16) char smem[40960];
  __shared__ float wt_lds[MT];

  int tid = threadIdx.x;
  int wv = tid >> 6, lane = tid & 63;
  int lo = lane & 15, hi = lane >> 4;

  if (tid < MT) {
    int g = base + tid;
    wt_lds[tid] = (g < cnt) ? wt_list[off + g] : 0.f;
  }

  // staging source pointers (fixed per thread; k advances via +ks)
  int rowA = tid >> 2;
  int jA = (tid & 3) ^ (rowA & 3);
  int tokA = tok_list[off + min(base + rowA, cnt - 1)];
  const unsigned short* srcA = xb + (size_t)tokA * H_ + jA * 8;

  const unsigned short* gb = gwb + (size_t)b * BS_ * H_;
  const unsigned short* ub = uwb + (size_t)b * BS_ * H_;
  const unsigned short* srcG[2];
  const unsigned short* srcU[2];
#pragma unroll
  for (int s = 0; s < 2; s++) {
    int o = s * 256 + tid;
    int c = o >> 2;
    int j = (o & 3) ^ (c & 3);
    size_t e = (size_t)c * H_ + j * 8;
    srcG[s] = gb + e;
    srcU[s] = ub + e;
  }

  f32x4 accG[4][2] = {};
  f32x4 accU[4][2] = {};

  // prologue stage buf0 @ ks=0
  {
    gl16(srcA, smem + wv * 1024);
#pragma unroll
    for (int s = 0; s < 2; s++) {
      gl16(srcG[s], smem + 8192 + s * 4096 + wv * 1024);
      gl16(srcU[s], smem + 24576 + s * 4096 + wv * 1024);
    }
  }
  __syncthreads();

  int cur = 0;
  for (int ks = 0; ks < H_; ks += 32) {
    if (ks + 32 < H_) {
      int nb_ = cur ^ 1;
      gl16(srcA + ks + 32, smem + nb_ * 4096 + wv * 1024);
#pragma unroll
      for (int s = 0; s < 2; s++) {
        gl16(srcG[s] + ks + 32, smem + 8192 + nb_ * 8192 + s * 4096 + wv * 1024);
        gl16(srcU[s] + ks + 32, smem + 24576 + nb_ * 8192 + s * 4096 + wv * 1024);
      }
    }
    bf16x8 Af[4];
#pragma unroll
    for (int m = 0; m < 4; m++) {
      int row = m * 16 + lo;
      int off16 = row * 4 + (hi ^ (lo & 3));
      Af[m] = lds8(smem + cur * 4096 + off16 * 16);
    }
    bf16x8 Gf[2], Uf[2];
#pragma unroll
    for (int cf = 0; cf < 2; cf++) {
      int c = wv * 32 + cf * 16 + lo;
      int off16 = c * 4 + (hi ^ (lo & 3));
      Gf[cf] = lds8(smem + 8192 + cur * 8192 + off16 * 16);
      Uf[cf] = lds8(smem + 24576 + cur * 8192 + off16 * 16);
    }
#pragma unroll
    for (int m = 0; m < 4; m++) {
#pragma unroll
      for (int cf = 0; cf < 2; cf++) {
        accG[m][cf] = __builtin_amdgcn_mfma_f32_16x16x32_bf16(Af[m], Gf[cf], accG[m][cf], 0, 0, 0);
        accU[m][cf] = __builtin_amdgcn_mfma_f32_16x16x32_bf16(Af[m], Uf[cf], accU[m][cf], 0, 0, 0);
      }
    }
    __syncthreads();
    cur ^= 1;
  }

  // ---- comp GEMM (K=64): lat (A) @24576, dec (B) @8192 ----
#pragma unroll
  for (int s = 0; s < 2; s++) {
    int o = s * 256 + tid;
    int r_ = o >> 3;
    int j = (o & 7) ^ (r_ & 7);
    int tokL = tok_list[off + min(base + r_, cnt - 1)];
    gl16(latb + (size_t)tokL * R_ + j * 8, smem + 24576 + s * 4096 + wv * 1024);
  }
  const unsigned short* decb = decb_all + (size_t)b * BS_ * R_;
#pragma unroll
  for (int s = 0; s < 4; s++) {
    int o = s * 256 + tid;
    int c = o >> 3;
    int j = (o & 7) ^ (c & 7);
    gl16(decb + (size_t)c * R_ + j * 8, smem + 8192 + s * 4096 + wv * 1024);
  }
  __syncthreads();

  f32x4 accC[4][2] = {};
#pragma unroll
  for (int kk = 0; kk < 2; kk++) {
    bf16x8 L[4];
#pragma unroll
    for (int m = 0; m < 4; m++) {
      int row = m * 16 + lo;
      int off16 = row * 8 + ((kk * 4 + hi) ^ (lo & 7));
      L[m] = lds8(smem + 24576 + off16 * 16);
    }
#pragma unroll
    for (int cf = 0; cf < 2; cf++) {
      int c = wv * 32 + cf * 16 + lo;
      int off16 = c * 8 + ((kk * 4 + hi) ^ (lo & 7));
      bf16x8 D = lds8(smem + 8192 + off16 * 16);
#pragma unroll
      for (int m = 0; m < 4; m++)
        accC[m][cf] = __builtin_amdgcn_mfma_f32_16x16x32_bf16(L[m], D, accC[m][cf], 0, 0, 0);
    }
  }

  // ---- epilogue ----
  float scal = scale_p[0];
  int cc[2] = { wv * 32 + lo, wv * 32 + 16 + lo };
  float bbv[2] = { bbias[b * BS_ + cc[0]], bbias[b * BS_ + cc[1]] };
#pragma unroll
  for (int m = 0; m < 4; m++) {
#pragma unroll
    for (int r = 0; r < 4; r++) {
      int t = m * 16 + hi * 4 + r;
      int g = base + t;
      if (g < cnt) {
        float wt = wt_lds[t];
        unsigned short* dst = actw + (size_t)(off + g) * BS_;
#pragma unroll
        for (int cf = 0; cf < 2; cf++) {
          float gg = accG[m][cf][r];
          float uu = accU[m][cf][r];
          float act = (gg / (1.f + __expf(-gg))) * uu;
          dst[cc[cf]] = f2bf((act + scal * (accC[m][cf][r] + bbv[cf])) * wt);
        }
      }
    }
  }
}

// ---------------- down: swapped operands, packed 8B stores ----------------
__global__ __launch_bounds__(256, 4) void down_kernel(
    const unsigned short* __restrict__ actw,
    const unsigned short* __restrict__ dwb,
    const int* __restrict__ counts,
    const int* __restrict__ offsets,
    unsigned short* __restrict__ partial,
    int hc0, int Hc) {
  int b, tile;
  if (!decode_bt(blockIdx.x, b, tile)) return;
  int cnt = counts[b];
  int base = tile * MT;
  if (base >= cnt) return;
  int off = offsets[b];

  __shared__ __align__(16) unsigned short a_lds[MT * BS_];
  int tid = threadIdx.x;
  for (int i = tid; i < MT * BS_ / 8; i += 256) {
    int t = i >> 4, cb = i & 15;
    int g = base + t;
    uint4 v = make_uint4(0, 0, 0, 0);
    if (g < cnt) v = *(const uint4*)(actw + (size_t)(off + g) * BS_ + cb * 8);
    *(uint4*)(&a_lds[t * BS_ + ((cb ^ (t & 7)) << 3)]) = v;
  }
  __syncthreads();

  int wv = tid >> 6, lane = tid & 63;
  int lo = lane & 15, hi = lane >> 4;
  const unsigned short* db = dwb + (size_t)b * H_ * BS_;

  for (int h0 = 0; h0 < Hc; h0 += 256) {
    int hw = hc0 + h0 + wv * 64;
    f32x4 acc[4][4] = {};
#pragma unroll
    for (int kst = 0; kst < 4; kst++) {
      bf16x8 Bf[4];
#pragma unroll
      for (int sf = 0; sf < 4; sf++) {
        int t = sf * 16 + lo, cb = kst * 4 + hi;
        Bf[sf] = ld8(&a_lds[t * BS_ + ((cb ^ (t & 7)) << 3)]);
      }
#pragma unroll
      for (int hm = 0; hm < 4; hm++) {
        bf16x8 Aw = ld8(db + (size_t)(hw + hm * 16 + lo) * BS_ + kst * 32 + hi * 8);
#pragma unroll
        for (int sf = 0; sf < 4; sf++)
          acc[hm][sf] = __builtin_amdgcn_mfma_f32_16x16x32_bf16(Aw, Bf[sf], acc[hm][sf], 0, 0, 0);
      }
    }
#pragma unroll
    for (int sf = 0; sf < 4; sf++) {
      int g = base + sf * 16 + lo;
      if (g < cnt) {
        unsigned short* pr = partial + (size_t)(off + g) * Hc;
#pragma unroll
        for (int hm = 0; hm < 4; hm++) {
          int hrel = h0 + wv * 64 + hm * 16 + hi * 4;
          uint2 pk;
          pk.x = (unsigned int)f2bf(acc[hm][sf][0]) | ((unsigned int)f2bf(acc[hm][sf][1]) << 16);
          pk.y = (unsigned int)f2bf(acc[hm][sf][2]) | ((unsigned int)f2bf(acc[hm][sf][3]) << 16);
          *(uint2*)(pr + hrel) = pk;
        }
      }
    }
  }
}

// ---------------- reduce ---------------------------------------------------
__global__ __launch_bounds__(256) void reduce_kernel(
    const unsigned short* __restrict__ partial,
    const int* __restrict__ inv,
    const float* __restrict__ cbias,
    float* __restrict__ out, int hc0, int Hc) {
  int wv = threadIdx.x >> 6, l = threadIdx.x & 63;
  int n = blockIdx.x * 4 + wv;
  int rows[K_];
#pragma unroll
  for (int k = 0; k < K_; k++) rows[k] = inv[n * K_ + k];
  for (int c0w = 0; c0w < Hc; c0w += 512) {
    int cw = c0w + l * 8;
    if (cw >= Hc) continue;
    float a[8] = {0.f, 0.f, 0.f, 0.f, 0.f, 0.f, 0.f, 0.f};
#pragma unroll
    for (int k = 0; k < K_; k++) {
      uint4 v = *(const uint4*)(partial + (size_t)rows[k] * Hc + cw);
      unsigned int w0 = v.x, w1 = v.y, w2 = v.z, w3 = v.w;
      a[0] += __uint_as_float(w0 << 16); a[1] += __uint_as_float(w0 & 0xFFFF0000u);
      a[2] += __uint_as_float(w1 << 16); a[3] += __uint_as_float(w1 & 0xFFFF0000u);
      a[4] += __uint_as_float(w2 << 16); a[5] += __uint_as_float(w2 & 0xFFFF0000u);
      a[6] += __uint_as_float(w3 << 16); a[7] += __uint_as_float(w3 & 0xFFFF0000u);
    }
    int h = hc0 + cw;
    float4 c0 = *(const float4*)(cbias + h);
    float4 c1 = *(const float4*)(cbias + h + 4);
    float4 o0 = make_float4(a[0] + c0.x, a[1] + c0.y, a[2] + c0.z, a[3] + c0.w);
    float4 o1 = make_float4(a[4] + c1.x, a[5] + c1.y, a[6] + c1.z, a[7] + c1.w);
    *(float4*)(out + (size_t)n * H_ + h) = o0;
    *(float4*)(out + (size_t)n * H_ + h + 4) = o1;
  }
}

// ---------------- launch ---------------------------------------------------
extern "C" void kernel_launch(void* const* d_in, const int* in_sizes, int n_in,
                              void* d_out, int out_size, void* d_ws, size_t ws_size,
                              hipStream_t stream) {
  const float* x       = (const float*)d_in[0];
  const int*   aidx    = (const int*)d_in[1];
  const float* score   = (const float*)d_in[2];
  const float* gate_w  = (const float*)d_in[3];
  const float* up_w    = (const float*)d_in[4];
  const float* down_w  = (const float*)d_in[5];
  const float* enc_w   = (const float*)d_in[6];
  const float* enc_b   = (const float*)d_in[7];
  const float* decoder = (const float*)d_in[8];
  const float* bbias   = (const float*)d_in[9];
  const float* cbias   = (const float*)d_in[10];
  const float* scale   = (const float*)d_in[11];
  float* out = (float*)d_out;

  char* ws = (char*)d_ws;
  const size_t OFF_GWB  = 33554432ull;
  const size_t OFF_UWB  = 56623104ull;
  const size_t OFF_DEC  = 79691776ull;
  const size_t OFF_LATB = 80412672ull;
  const size_t OFF_WBUF = 81461248ull;
  const size_t OFF_TOK  = 81723392ull;
  const size_t OFF_WT   = 81985536ull;
  const size_t OFF_INV  = 82247680ull;
  const size_t OFF_CNT  = 82509824ull;
  const size_t OFF_ACTW = 82510848ull;
  const size_t BASE_END = 99288064ull;
  const size_t DWB_SZ   = 23068672ull;

  unsigned short* xb   = (unsigned short*)(ws);
  unsigned short* gwb  = (unsigned short*)(ws + OFF_GWB);
  unsigned short* uwb  = (unsigned short*)(ws + OFF_UWB);
  unsigned short* decb = (unsigned short*)(ws + OFF_DEC);
  unsigned short* latb = (unsigned short*)(ws + OFF_LATB);
  float* w_buf         = (float*)(ws + OFF_WBUF);
  int*   tok_list      = (int*)(ws + OFF_TOK);
  float* wt_list       = (float*)(ws + OFF_WT);
  int*   inv           = (int*)(ws + OFF_INV);
  int*   counts        = (int*)(ws + OFF_CNT);
  int*   offsets       = counts + 64;
  int*   cursors       = counts + 128;
  unsigned short* actw = (unsigned short*)(ws + OFF_ACTW);

  int Hc; unsigned short* dwb; unsigned short* partial; bool early_down;
  if      (ws_size >= BASE_END + DWB_SZ + 131072ull * 2048) Hc = 2048;
  else if (ws_size >= BASE_END + DWB_SZ + 131072ull * 1024) Hc = 1024;
  else if (ws_size >= BASE_END + DWB_SZ + 131072ull * 512)  Hc = 512;
  else if (ws_size >= BASE_END + DWB_SZ + 131072ull * 256)  Hc = 256;
  else Hc = 0;
  if (Hc) {
    early_down = true;
    dwb = (unsigned short*)(ws + BASE_END);
    partial = (unsigned short*)(ws + BASE_END + DWB_SZ);
  } else {
    early_down = false;
    Hc = 256;
    dwb = gwb;
    partial = (unsigned short*)ws;
  }
  int nch = H_ / Hc;

  cvt_xgu<<<2048, 256, 0, stream>>>(x, gate_w, up_w, xb, gwb, uwb);
  cvt_dec<<<(NB_ * BS_ * R_ + 255) / 256, 256, 0, stream>>>(decoder, decb);
  if (early_down) cvt_down<<<2048, 256, 0, stream>>>(down_w, dwb);
  zero_counts<<<1, 64, 0, stream>>>(counts);
  prep_kernel<<<N_ / 256, 256, 0, stream>>>(score, aidx, w_buf, counts);
  scan_kernel<<<1, 64, 0, stream>>>(counts, offsets, cursors);
  fill_kernel<<<N_ / 256, 256, 0, stream>>>(aidx, w_buf, cursors, tok_list, wt_list, inv);
  latent_kernel<<<N_ / 16, 256, 0, stream>>>(xb, enc_w, enc_b, latb);
  gateup_kernel<<<GRID_AB, 256, 0, stream>>>(xb, gwb, uwb, latb, decb, bbias, scale,
                                             counts, offsets, tok_list, wt_list, actw);
  if (!early_down) cvt_down<<<2048, 256, 0, stream>>>(down_w, dwb);
  for (int c = 0; c < nch; c++) {
    down_kernel<<<GRID_AB, 256, 0, stream>>>(actw, dwb, counts, offsets, partial, c * Hc, Hc);
    reduce_kernel<<<N_ / 4, 256, 0, stream>>>(partial, inv, cbias, out, c * Hc, Hc);
  }
}

// Round 4
// 702.045 us; speedup vs baseline: 2.1446x; 1.1952x over previous
//
#include <hip/hip_runtime.h>

#define H_  2048
#define BS_ 128
#define NB_ 44
#define R_  64
#define K_  8
#define N_  8192
#define I_  5632
#define MT  64
#define TILES 32
#define GRID_AB (8 * 6 * TILES)

typedef __bf16 bf16x8 __attribute__((ext_vector_type(8)));
typedef float  f32x4  __attribute__((ext_vector_type(4)));

__device__ __forceinline__ unsigned short f2bf(float f) {
  unsigned int u = __float_as_uint(f);
  u = (u + 0x7FFFu + ((u >> 16) & 1u)) >> 16;
  return (unsigned short)u;
}
__device__ __forceinline__ float bf2f(unsigned short s) {
  return __uint_as_float(((unsigned int)s) << 16);
}
__device__ __forceinline__ bf16x8 ld8(const unsigned short* p) {
  uint4 v = *reinterpret_cast<const uint4*>(p);
  return __builtin_bit_cast(bf16x8, v);
}
__device__ __forceinline__ bf16x8 lds8(const char* p) {
  uint4 v = *reinterpret_cast<const uint4*>(p);
  return __builtin_bit_cast(bf16x8, v);
}
__device__ __forceinline__ void gl16(const void* g, void* l) {
  __builtin_amdgcn_global_load_lds(
      (const __attribute__((address_space(1))) char*)g,
      (__attribute__((address_space(3))) char*)l, 16, 0, 0);
}

// ---------------- conversions ---------------------------------------------
__global__ void cvt_xgu(const float* __restrict__ x, const float* __restrict__ gw,
                        const float* __restrict__ uw, const float* __restrict__ ew,
                        unsigned short* __restrict__ xb,
                        unsigned short* __restrict__ gwb,
                        unsigned short* __restrict__ uwb,
                        unsigned short* __restrict__ ewb) {
  const int NX4 = N_ * H_ / 4;
  const int NG4 = I_ * H_ / 4;
  const int NE4 = R_ * H_ / 4;
  int total = NX4 + 2 * NG4 + NE4;
  int stride = gridDim.x * blockDim.x;
  for (int i = blockIdx.x * blockDim.x + threadIdx.x; i < total; i += stride) {
    const float4* s; ushort4* d; int j;
    if (i < NX4)                  { s = (const float4*)x;  d = (ushort4*)xb;  j = i; }
    else if (i < NX4 + NG4)       { s = (const float4*)gw; d = (ushort4*)gwb; j = i - NX4; }
    else if (i < NX4 + 2 * NG4)   { s = (const float4*)uw; d = (ushort4*)uwb; j = i - NX4 - NG4; }
    else                          { s = (const float4*)ew; d = (ushort4*)ewb; j = i - NX4 - 2 * NG4; }
    float4 v = s[j];
    ushort4 o; o.x = f2bf(v.x); o.y = f2bf(v.y); o.z = f2bf(v.z); o.w = f2bf(v.w);
    d[j] = o;
  }
}

// down_w [H][I] f32 -> dwb [NB][H][128] bf16
__global__ void cvt_down(const float* __restrict__ dw, unsigned short* __restrict__ dwb) {
  int total = H_ * I_ / 4;
  int stride = gridDim.x * blockDim.x;
  for (int i = blockIdx.x * blockDim.x + threadIdx.x; i < total; i += stride) {
    float4 v = ((const float4*)dw)[i];
    int flat = i * 4;
    int h = flat / I_;
    int rem = flat - h * I_;
    int b = rem >> 7, k = rem & 127;
    ushort4 o; o.x = f2bf(v.x); o.y = f2bf(v.y); o.z = f2bf(v.z); o.w = f2bf(v.w);
    *(ushort4*)(dwb + ((size_t)b * H_ + h) * BS_ + k) = o;
  }
}

// decoder [NB][R][BS] f32 -> dec_bf [NB][BS][R] bf16 (transposed)
__global__ void cvt_dec(const float* __restrict__ dec, unsigned short* __restrict__ decb) {
  int i = blockIdx.x * 256 + threadIdx.x;
  if (i >= NB_ * BS_ * R_) return;
  int b = i >> 13;
  int rem = i & 8191;
  int c = rem >> 6, r = rem & 63;
  decb[i] = f2bf(dec[(b << 13) + r * BS_ + c]);
}

// ---------------- routing prep --------------------------------------------
__global__ void zero_counts(int* __restrict__ counts) {
  if (threadIdx.x < NB_) counts[threadIdx.x] = 0;
}

__global__ void prep_kernel(const float* __restrict__ score,
                            const int* __restrict__ aidx,
                            float* __restrict__ w_buf,
                            int* __restrict__ counts) {
  __shared__ int hist[NB_];
  int tid = threadIdx.x;
  if (tid < NB_) hist[tid] = 0;
  __syncthreads();
  int n = blockIdx.x * 256 + tid;
  float s[K_];
  float m = -1e30f;
#pragma unroll
  for (int k = 0; k < K_; k++) { s[k] = score[n * K_ + k]; m = fmaxf(m, s[k]); }
  float sum = 0.f;
#pragma unroll
  for (int k = 0; k < K_; k++) { s[k] = __expf(s[k] - m); sum += s[k]; }
  float inv = 1.f / sum;
#pragma unroll
  for (int k = 0; k < K_; k++) {
    w_buf[n * K_ + k] = s[k] * inv;
    atomicAdd(&hist[aidx[n * K_ + k]], 1);
  }
  __syncthreads();
  if (tid < NB_) atomicAdd(&counts[tid], hist[tid]);
}

__global__ void scan_kernel(const int* __restrict__ counts,
                            int* __restrict__ offsets,
                            int* __restrict__ cursors) {
  if (threadIdx.x == 0) {
    int acc = 0;
    for (int b = 0; b < NB_; b++) { offsets[b] = acc; cursors[b] = acc; acc += counts[b]; }
    offsets[NB_] = acc;
  }
}

__global__ void fill_kernel(const int* __restrict__ aidx,
                            const float* __restrict__ w_buf,
                            int* __restrict__ cursors,
                            int* __restrict__ tok_list,
                            float* __restrict__ wt_list,
                            int* __restrict__ inv) {
  int n = blockIdx.x * 256 + threadIdx.x;
#pragma unroll
  for (int k = 0; k < K_; k++) {
    int b = aidx[n * K_ + k];
    int pos = atomicAdd(&cursors[b], 1);
    tok_list[pos] = n;
    wt_list[pos] = w_buf[n * K_ + k];
    inv[n * K_ + k] = pos;
  }
}

// ---------------- latent via MFMA: lat = silu(x @ enc_w.T + enc_b) --------
// block: 64 tokens x 64 R, K=2048. A dbuf 2x4KB @0, B dbuf 2x4KB @8192.
__global__ __launch_bounds__(256) void latent_mfma(
    const unsigned short* __restrict__ xb,
    const unsigned short* __restrict__ ewb,
    const float* __restrict__ enc_b,
    unsigned short* __restrict__ lat) {
  __shared__ __align__(16) char smem[16384];
  int tid = threadIdx.x;
  int wv = tid >> 6, lane = tid & 63;
  int lo = lane & 15, hi = lane >> 4;
  int n0 = blockIdx.x * 64;

  int rowA = tid >> 2;
  int jA = (tid & 3) ^ (rowA & 3);
  const unsigned short* srcA = xb + (size_t)(n0 + rowA) * H_ + jA * 8;
  const unsigned short* srcB = ewb + (size_t)rowA * H_ + jA * 8;

  gl16(srcA, smem + wv * 1024);
  gl16(srcB, smem + 8192 + wv * 1024);
  __syncthreads();

  f32x4 acc[4] = {};
  int cur = 0;
  for (int ks = 0; ks < H_; ks += 32) {
    if (ks + 32 < H_) {
      gl16(srcA + ks + 32, smem + (cur ^ 1) * 4096 + wv * 1024);
      gl16(srcB + ks + 32, smem + 8192 + (cur ^ 1) * 4096 + wv * 1024);
    }
    int rB = wv * 16 + lo;
    bf16x8 Bf = lds8(smem + 8192 + cur * 4096 + (rB * 4 + (hi ^ (lo & 3))) * 16);
#pragma unroll
    for (int m = 0; m < 4; m++) {
      int row = m * 16 + lo;
      bf16x8 Af = lds8(smem + cur * 4096 + (row * 4 + (hi ^ (lo & 3))) * 16);
      acc[m] = __builtin_amdgcn_mfma_f32_16x16x32_bf16(Af, Bf, acc[m], 0, 0, 0);
    }
    __syncthreads();
    cur ^= 1;
  }

  int r = wv * 16 + lo;
  float eb = enc_b[r];
#pragma unroll
  for (int m = 0; m < 4; m++) {
#pragma unroll
    for (int rg = 0; rg < 4; rg++) {
      int tok = n0 + m * 16 + hi * 4 + rg;
      float v = acc[m][rg] + eb;
      lat[(size_t)tok * R_ + r] = f2bf(v / (1.f + __expf(-v)));
    }
  }
}

__device__ __forceinline__ bool decode_bt(int p, int& b, int& tile) {
  b = (p & 7) + 8 * ((p >> 3) / TILES);
  tile = (p >> 3) % TILES;
  return b < NB_;
}

// ---------------- gateup: pipelined LDS GEMM + MFMA comp ------------------
__global__ __launch_bounds__(256, 3) void gateup_kernel(
    const unsigned short* __restrict__ xb,
    const unsigned short* __restrict__ gwb,
    const unsigned short* __restrict__ uwb,
    const unsigned short* __restrict__ latb,
    const unsigned short* __restrict__ decb_all,
    const float* __restrict__ bbias,
    const float* __restrict__ scale_p,
    const int* __restrict__ counts,
    const int* __restrict__ offsets,
    const int* __restrict__ tok_list,
    const float* __restrict__ wt_list,
    unsigned short* __restrict__ actw) {
  int b, tile;
  if (!decode_bt(blockIdx.x, b, tile)) return;
  int cnt = counts[b];
  int base = tile * MT;
  if (base >= cnt) return;
  int off = offsets[b];

  __shared__ __align__(16) char smem[40960];
  __shared__ float wt_lds[MT];

  int tid = threadIdx.x;
  int wv = tid >> 6, lane = tid & 63;
  int lo = lane & 15, hi = lane >> 4;

  if (tid < MT) {
    int g = base + tid;
    wt_lds[tid] = (g < cnt) ? wt_list[off + g] : 0.f;
  }

  int rowA = tid >> 2;
  int jA = (tid & 3) ^ (rowA & 3);
  int tokA = tok_list[off + min(base + rowA, cnt - 1)];
  const unsigned short* srcA = xb + (size_t)tokA * H_ + jA * 8;

  const unsigned short* gb = gwb + (size_t)b * BS_ * H_;
  const unsigned short* ub = uwb + (size_t)b * BS_ * H_;
  const unsigned short* srcG[2];
  const unsigned short* srcU[2];
#pragma unroll
  for (int s = 0; s < 2; s++) {
    int o = s * 256 + tid;
    int c = o >> 2;
    int j = (o & 3) ^ (c & 3);
    size_t e = (size_t)c * H_ + j * 8;
    srcG[s] = gb + e;
    srcU[s] = ub + e;
  }

  f32x4 accG[4][2] = {};
  f32x4 accU[4][2] = {};

  {
    gl16(srcA, smem + wv * 1024);
#pragma unroll
    for (int s = 0; s < 2; s++) {
      gl16(srcG[s], smem + 8192 + s * 4096 + wv * 1024);
      gl16(srcU[s], smem + 24576 + s * 4096 + wv * 1024);
    }
  }
  __syncthreads();

  int cur = 0;
  for (int ks = 0; ks < H_; ks += 32) {
    if (ks + 32 < H_) {
      int nb_ = cur ^ 1;
      gl16(srcA + ks + 32, smem + nb_ * 4096 + wv * 1024);
#pragma unroll
      for (int s = 0; s < 2; s++) {
        gl16(srcG[s] + ks + 32, smem + 8192 + nb_ * 8192 + s * 4096 + wv * 1024);
        gl16(srcU[s] + ks + 32, smem + 24576 + nb_ * 8192 + s * 4096 + wv * 1024);
      }
    }
    bf16x8 Af[4];
#pragma unroll
    for (int m = 0; m < 4; m++) {
      int row = m * 16 + lo;
      int off16 = row * 4 + (hi ^ (lo & 3));
      Af[m] = lds8(smem + cur * 4096 + off16 * 16);
    }
    bf16x8 Gf[2], Uf[2];
#pragma unroll
    for (int cf = 0; cf < 2; cf++) {
      int c = wv * 32 + cf * 16 + lo;
      int off16 = c * 4 + (hi ^ (lo & 3));
      Gf[cf] = lds8(smem + 8192 + cur * 8192 + off16 * 16);
      Uf[cf] = lds8(smem + 24576 + cur * 8192 + off16 * 16);
    }
#pragma unroll
    for (int m = 0; m < 4; m++) {
#pragma unroll
      for (int cf = 0; cf < 2; cf++) {
        accG[m][cf] = __builtin_amdgcn_mfma_f32_16x16x32_bf16(Af[m], Gf[cf], accG[m][cf], 0, 0, 0);
        accU[m][cf] = __builtin_amdgcn_mfma_f32_16x16x32_bf16(Af[m], Uf[cf], accU[m][cf], 0, 0, 0);
      }
    }
    __syncthreads();
    cur ^= 1;
  }

  // ---- comp GEMM (K=64): lat (A) @24576, dec (B) @8192 ----
#pragma unroll
  for (int s = 0; s < 2; s++) {
    int o = s * 256 + tid;
    int r_ = o >> 3;
    int j = (o & 7) ^ (r_ & 7);
    int tokL = tok_list[off + min(base + r_, cnt - 1)];
    gl16(latb + (size_t)tokL * R_ + j * 8, smem + 24576 + s * 4096 + wv * 1024);
  }
  const unsigned short* decb = decb_all + (size_t)b * BS_ * R_;
#pragma unroll
  for (int s = 0; s < 4; s++) {
    int o = s * 256 + tid;
    int c = o >> 3;
    int j = (o & 7) ^ (c & 7);
    gl16(decb + (size_t)c * R_ + j * 8, smem + 8192 + s * 4096 + wv * 1024);
  }
  __syncthreads();

  f32x4 accC[4][2] = {};
#pragma unroll
  for (int kk = 0; kk < 2; kk++) {
    bf16x8 L[4];
#pragma unroll
    for (int m = 0; m < 4; m++) {
      int row = m * 16 + lo;
      int off16 = row * 8 + ((kk * 4 + hi) ^ (lo & 7));
      L[m] = lds8(smem + 24576 + off16 * 16);
    }
#pragma unroll
    for (int cf = 0; cf < 2; cf++) {
      int c = wv * 32 + cf * 16 + lo;
      int off16 = c * 8 + ((kk * 4 + hi) ^ (lo & 7));
      bf16x8 D = lds8(smem + 8192 + off16 * 16);
#pragma unroll
      for (int m = 0; m < 4; m++)
        accC[m][cf] = __builtin_amdgcn_mfma_f32_16x16x32_bf16(L[m], D, accC[m][cf], 0, 0, 0);
    }
  }

  float scal = scale_p[0];
  int cc[2] = { wv * 32 + lo, wv * 32 + 16 + lo };
  float bbv[2] = { bbias[b * BS_ + cc[0]], bbias[b * BS_ + cc[1]] };
#pragma unroll
  for (int m = 0; m < 4; m++) {
#pragma unroll
    for (int r = 0; r < 4; r++) {
      int t = m * 16 + hi * 4 + r;
      int g = base + t;
      if (g < cnt) {
        float wt = wt_lds[t];
        unsigned short* dst = actw + (size_t)(off + g) * BS_;
#pragma unroll
        for (int cf = 0; cf < 2; cf++) {
          float gg = accG[m][cf][r];
          float uu = accU[m][cf][r];
          float act = (gg / (1.f + __expf(-gg))) * uu;
          dst[cc[cf]] = f2bf((act + scal * (accC[m][cf][r] + bbv[cf])) * wt);
        }
      }
    }
  }
}

// ---------------- down: swapped operands, packed 8B stores ----------------
__global__ __launch_bounds__(256, 4) void down_kernel(
    const unsigned short* __restrict__ actw,
    const unsigned short* __restrict__ dwb,
    const int* __restrict__ counts,
    const int* __restrict__ offsets,
    unsigned short* __restrict__ partial,
    int hc0, int Hc) {
  int b, tile;
  if (!decode_bt(blockIdx.x, b, tile)) return;
  int cnt = counts[b];
  int base = tile * MT;
  if (base >= cnt) return;
  int off = offsets[b];

  __shared__ __align__(16) unsigned short a_lds[MT * BS_];
  int tid = threadIdx.x;
  for (int i = tid; i < MT * BS_ / 8; i += 256) {
    int t = i >> 4, cb = i & 15;
    int g = base + t;
    uint4 v = make_uint4(0, 0, 0, 0);
    if (g < cnt) v = *(const uint4*)(actw + (size_t)(off + g) * BS_ + cb * 8);
    *(uint4*)(&a_lds[t * BS_ + ((cb ^ (t & 7)) << 3)]) = v;
  }
  __syncthreads();

  int wv = tid >> 6, lane = tid & 63;
  int lo = lane & 15, hi = lane >> 4;
  const unsigned short* db = dwb + (size_t)b * H_ * BS_;

  for (int h0 = 0; h0 < Hc; h0 += 256) {
    int hw = hc0 + h0 + wv * 64;
    f32x4 acc[4][4] = {};
#pragma unroll
    for (int kst = 0; kst < 4; kst++) {
      bf16x8 Bf[4];
#pragma unroll
      for (int sf = 0; sf < 4; sf++) {
        int t = sf * 16 + lo, cb = kst * 4 + hi;
        Bf[sf] = ld8(&a_lds[t * BS_ + ((cb ^ (t & 7)) << 3)]);
      }
#pragma unroll
      for (int hm = 0; hm < 4; hm++) {
        bf16x8 Aw = ld8(db + (size_t)(hw + hm * 16 + lo) * BS_ + kst * 32 + hi * 8);
#pragma unroll
        for (int sf = 0; sf < 4; sf++)
          acc[hm][sf] = __builtin_amdgcn_mfma_f32_16x16x32_bf16(Aw, Bf[sf], acc[hm][sf], 0, 0, 0);
      }
    }
#pragma unroll
    for (int sf = 0; sf < 4; sf++) {
      int g = base + sf * 16 + lo;
      if (g < cnt) {
        unsigned short* pr = partial + (size_t)(off + g) * Hc;
#pragma unroll
        for (int hm = 0; hm < 4; hm++) {
          int hrel = h0 + wv * 64 + hm * 16 + hi * 4;
          uint2 pk;
          pk.x = (unsigned int)f2bf(acc[hm][sf][0]) | ((unsigned int)f2bf(acc[hm][sf][1]) << 16);
          pk.y = (unsigned int)f2bf(acc[hm][sf][2]) | ((unsigned int)f2bf(acc[hm][sf][3]) << 16);
          *(uint2*)(pr + hrel) = pk;
        }
      }
    }
  }
}

// ---------------- reduce ---------------------------------------------------
__global__ __launch_bounds__(256) void reduce_kernel(
    const unsigned short* __restrict__ partial,
    const int* __restrict__ inv,
    const float* __restrict__ cbias,
    float* __restrict__ out, int hc0, int Hc) {
  int wv = threadIdx.x >> 6, l = threadIdx.x & 63;
  int n = blockIdx.x * 4 + wv;
  int rows[K_];
#pragma unroll
  for (int k = 0; k < K_; k++) rows[k] = inv[n * K_ + k];
  for (int c0w = 0; c0w < Hc; c0w += 512) {
    int cw = c0w + l * 8;
    if (cw >= Hc) continue;
    float a[8] = {0.f, 0.f, 0.f, 0.f, 0.f, 0.f, 0.f, 0.f};
#pragma unroll
    for (int k = 0; k < K_; k++) {
      uint4 v = *(const uint4*)(partial + (size_t)rows[k] * Hc + cw);
      unsigned int w0 = v.x, w1 = v.y, w2 = v.z, w3 = v.w;
      a[0] += __uint_as_float(w0 << 16); a[1] += __uint_as_float(w0 & 0xFFFF0000u);
      a[2] += __uint_as_float(w1 << 16); a[3] += __uint_as_float(w1 & 0xFFFF0000u);
      a[4] += __uint_as_float(w2 << 16); a[5] += __uint_as_float(w2 & 0xFFFF0000u);
      a[6] += __uint_as_float(w3 << 16); a[7] += __uint_as_float(w3 & 0xFFFF0000u);
    }
    int h = hc0 + cw;
    float4 c0 = *(const float4*)(cbias + h);
    float4 c1 = *(const float4*)(cbias + h + 4);
    float4 o0 = make_float4(a[0] + c0.x, a[1] + c0.y, a[2] + c0.z, a[3] + c0.w);
    float4 o1 = make_float4(a[4] + c1.x, a[5] + c1.y, a[6] + c1.z, a[7] + c1.w);
    *(float4*)(out + (size_t)n * H_ + h) = o0;
    *(float4*)(out + (size_t)n * H_ + h + 4) = o1;
  }
}

// ---------------- launch ---------------------------------------------------
extern "C" void kernel_launch(void* const* d_in, const int* in_sizes, int n_in,
                              void* d_out, int out_size, void* d_ws, size_t ws_size,
                              hipStream_t stream) {
  const float* x       = (const float*)d_in[0];
  const int*   aidx    = (const int*)d_in[1];
  const float* score   = (const float*)d_in[2];
  const float* gate_w  = (const float*)d_in[3];
  const float* up_w    = (const float*)d_in[4];
  const float* down_w  = (const float*)d_in[5];
  const float* enc_w   = (const float*)d_in[6];
  const float* enc_b   = (const float*)d_in[7];
  const float* decoder = (const float*)d_in[8];
  const float* bbias   = (const float*)d_in[9];
  const float* cbias   = (const float*)d_in[10];
  const float* scale   = (const float*)d_in[11];
  float* out = (float*)d_out;

  char* ws = (char*)d_ws;
  const size_t OFF_GWB  = 33554432ull;
  const size_t OFF_UWB  = 56623104ull;
  const size_t OFF_DEC  = 79691776ull;
  const size_t OFF_LATB = 80412672ull;
  const size_t OFF_ENCB = 81461248ull;
  const size_t OFF_WBUF = 81723392ull;
  const size_t OFF_TOK  = 81985536ull;
  const size_t OFF_WT   = 82247680ull;
  const size_t OFF_INV  = 82509824ull;
  const size_t OFF_CNT  = 82771968ull;
  const size_t OFF_ACTW = 82772992ull;
  const size_t BASE_END = 99550208ull;
  const size_t DWB_SZ   = 23068672ull;

  unsigned short* xb   = (unsigned short*)(ws);
  unsigned short* gwb  = (unsigned short*)(ws + OFF_GWB);
  unsigned short* uwb  = (unsigned short*)(ws + OFF_UWB);
  unsigned short* decb = (unsigned short*)(ws + OFF_DEC);
  unsigned short* latb = (unsigned short*)(ws + OFF_LATB);
  unsigned short* ewb  = (unsigned short*)(ws + OFF_ENCB);
  float* w_buf         = (float*)(ws + OFF_WBUF);
  int*   tok_list      = (int*)(ws + OFF_TOK);
  float* wt_list       = (float*)(ws + OFF_WT);
  int*   inv           = (int*)(ws + OFF_INV);
  int*   counts        = (int*)(ws + OFF_CNT);
  int*   offsets       = counts + 64;
  int*   cursors       = counts + 128;
  unsigned short* actw = (unsigned short*)(ws + OFF_ACTW);

  int Hc; unsigned short* dwb; unsigned short* partial; bool early_down;
  if      (ws_size >= BASE_END + DWB_SZ + 131072ull * 2048) Hc = 2048;
  else if (ws_size >= BASE_END + DWB_SZ + 131072ull * 1024) Hc = 1024;
  else if (ws_size >= BASE_END + DWB_SZ + 131072ull * 512)  Hc = 512;
  else if (ws_size >= BASE_END + DWB_SZ + 131072ull * 256)  Hc = 256;
  else Hc = 0;
  if (Hc) {
    early_down = true;
    dwb = (unsigned short*)(ws + BASE_END);
    partial = (unsigned short*)(ws + BASE_END + DWB_SZ);
  } else {
    early_down = false;
    Hc = 256;
    dwb = gwb;
    partial = (unsigned short*)ws;
  }
  int nch = H_ / Hc;

  cvt_xgu<<<2048, 256, 0, stream>>>(x, gate_w, up_w, enc_w, xb, gwb, uwb, ewb);
  cvt_dec<<<(NB_ * BS_ * R_ + 255) / 256, 256, 0, stream>>>(decoder, decb);
  if (early_down) cvt_down<<<2048, 256, 0, stream>>>(down_w, dwb);
  zero_counts<<<1, 64, 0, stream>>>(counts);
  prep_kernel<<<N_ / 256, 256, 0, stream>>>(score, aidx, w_buf, counts);
  scan_kernel<<<1, 64, 0, stream>>>(counts, offsets, cursors);
  fill_kernel<<<N_ / 256, 256, 0, stream>>>(aidx, w_buf, cursors, tok_list, wt_list, inv);
  latent_mfma<<<N_ / 64, 256, 0, stream>>>(xb, ewb, enc_b, latb);
  gateup_kernel<<<GRID_AB, 256, 0, stream>>>(xb, gwb, uwb, latb, decb, bbias, scale,
                                             counts, offsets, tok_list, wt_list, actw);
  if (!early_down) cvt_down<<<2048, 256, 0, stream>>>(down_w, dwb);
  for (int c = 0; c < nch; c++) {
    down_kernel<<<GRID_AB, 256, 0, stream>>>(actw, dwb, counts, offsets, partial, c * Hc, Hc);
    reduce_kernel<<<N_ / 4, 256, 0, stream>>>(partial, inv, cbias, out, c * Hc, Hc);
  }
}

// Round 5
// 534.083 us; speedup vs baseline: 2.8191x; 1.3145x over previous
//
#include <hip/hip_runtime.h>

#define H_  2048
#define BS_ 128
#define NB_ 44
#define R_  64
#define K_  8
#define N_  8192
#define I_  5632
#define MT  64
#define TILES 32
#define GRID_AB (8 * 6 * TILES)

typedef __bf16 bf16x8 __attribute__((ext_vector_type(8)));
typedef float  f32x4  __attribute__((ext_vector_type(4)));

__device__ __forceinline__ unsigned short f2bf(float f) {
  unsigned int u = __float_as_uint(f);
  u = (u + 0x7FFFu + ((u >> 16) & 1u)) >> 16;
  return (unsigned short)u;
}
__device__ __forceinline__ float bf2f(unsigned short s) {
  return __uint_as_float(((unsigned int)s) << 16);
}
__device__ __forceinline__ bf16x8 ld8(const unsigned short* p) {
  uint4 v = *reinterpret_cast<const uint4*>(p);
  return __builtin_bit_cast(bf16x8, v);
}
__device__ __forceinline__ bf16x8 lds8(const char* p) {
  uint4 v = *reinterpret_cast<const uint4*>(p);
  return __builtin_bit_cast(bf16x8, v);
}
__device__ __forceinline__ void gl16(const void* g, void* l) {
  __builtin_amdgcn_global_load_lds(
      (const __attribute__((address_space(1))) char*)g,
      (__attribute__((address_space(3))) char*)l, 16, 0, 0);
}

// ---------------- conversions ---------------------------------------------
__global__ void cvt_xgu(const float* __restrict__ x, const float* __restrict__ gw,
                        const float* __restrict__ uw, const float* __restrict__ ew,
                        unsigned short* __restrict__ xb,
                        unsigned short* __restrict__ gwb,
                        unsigned short* __restrict__ uwb,
                        unsigned short* __restrict__ ewb) {
  const int NX4 = N_ * H_ / 4;
  const int NG4 = I_ * H_ / 4;
  const int NE4 = R_ * H_ / 4;
  int total = NX4 + 2 * NG4 + NE4;
  int stride = gridDim.x * blockDim.x;
  for (int i = blockIdx.x * blockDim.x + threadIdx.x; i < total; i += stride) {
    const float4* s; ushort4* d; int j;
    if (i < NX4)                  { s = (const float4*)x;  d = (ushort4*)xb;  j = i; }
    else if (i < NX4 + NG4)       { s = (const float4*)gw; d = (ushort4*)gwb; j = i - NX4; }
    else if (i < NX4 + 2 * NG4)   { s = (const float4*)uw; d = (ushort4*)uwb; j = i - NX4 - NG4; }
    else                          { s = (const float4*)ew; d = (ushort4*)ewb; j = i - NX4 - 2 * NG4; }
    float4 v = s[j];
    ushort4 o; o.x = f2bf(v.x); o.y = f2bf(v.y); o.z = f2bf(v.z); o.w = f2bf(v.w);
    d[j] = o;
  }
}

// down_w [H][I] f32 -> dwb [NB][H][128] bf16
__global__ void cvt_down(const float* __restrict__ dw, unsigned short* __restrict__ dwb) {
  int total = H_ * I_ / 4;
  int stride = gridDim.x * blockDim.x;
  for (int i = blockIdx.x * blockDim.x + threadIdx.x; i < total; i += stride) {
    float4 v = ((const float4*)dw)[i];
    int flat = i * 4;
    int h = flat / I_;
    int rem = flat - h * I_;
    int b = rem >> 7, k = rem & 127;
    ushort4 o; o.x = f2bf(v.x); o.y = f2bf(v.y); o.z = f2bf(v.z); o.w = f2bf(v.w);
    *(ushort4*)(dwb + ((size_t)b * H_ + h) * BS_ + k) = o;
  }
}

// decoder [NB][R][BS] f32 -> dec_bf [NB][BS][R] bf16 (transposed)
__global__ void cvt_dec(const float* __restrict__ dec, unsigned short* __restrict__ decb) {
  int i = blockIdx.x * 256 + threadIdx.x;
  if (i >= NB_ * BS_ * R_) return;
  int b = i >> 13;
  int rem = i & 8191;
  int c = rem >> 6, r = rem & 63;
  decb[i] = f2bf(dec[(b << 13) + r * BS_ + c]);
}

// ---------------- routing prep --------------------------------------------
__global__ void zero_counts(int* __restrict__ counts) {
  if (threadIdx.x < NB_) counts[threadIdx.x] = 0;
}

__global__ void prep_kernel(const float* __restrict__ score,
                            const int* __restrict__ aidx,
                            float* __restrict__ w_buf,
                            int* __restrict__ counts) {
  __shared__ int hist[NB_];
  int tid = threadIdx.x;
  if (tid < NB_) hist[tid] = 0;
  __syncthreads();
  int n = blockIdx.x * 256 + tid;
  float s[K_];
  float m = -1e30f;
#pragma unroll
  for (int k = 0; k < K_; k++) { s[k] = score[n * K_ + k]; m = fmaxf(m, s[k]); }
  float sum = 0.f;
#pragma unroll
  for (int k = 0; k < K_; k++) { s[k] = __expf(s[k] - m); sum += s[k]; }
  float inv = 1.f / sum;
#pragma unroll
  for (int k = 0; k < K_; k++) {
    w_buf[n * K_ + k] = s[k] * inv;
    atomicAdd(&hist[aidx[n * K_ + k]], 1);
  }
  __syncthreads();
  if (tid < NB_) atomicAdd(&counts[tid], hist[tid]);
}

__global__ void scan_kernel(const int* __restrict__ counts,
                            int* __restrict__ offsets,
                            int* __restrict__ cursors) {
  if (threadIdx.x == 0) {
    int acc = 0;
    for (int b = 0; b < NB_; b++) { offsets[b] = acc; cursors[b] = acc; acc += counts[b]; }
    offsets[NB_] = acc;
  }
}

__global__ void fill_kernel(const int* __restrict__ aidx,
                            const float* __restrict__ w_buf,
                            int* __restrict__ cursors,
                            int* __restrict__ tok_list,
                            float* __restrict__ wt_list,
                            int* __restrict__ inv) {
  int n = blockIdx.x * 256 + threadIdx.x;
#pragma unroll
  for (int k = 0; k < K_; k++) {
    int b = aidx[n * K_ + k];
    int pos = atomicAdd(&cursors[b], 1);
    tok_list[pos] = n;
    wt_list[pos] = w_buf[n * K_ + k];
    inv[n * K_ + k] = pos;
  }
}

// ---------------- latent via MFMA -----------------------------------------
__global__ __launch_bounds__(256) void latent_mfma(
    const unsigned short* __restrict__ xb,
    const unsigned short* __restrict__ ewb,
    const float* __restrict__ enc_b,
    unsigned short* __restrict__ lat) {
  __shared__ __align__(16) char smem[16384];
  int tid = threadIdx.x;
  int wv = tid >> 6, lane = tid & 63;
  int lo = lane & 15, hi = lane >> 4;
  int n0 = blockIdx.x * 64;

  int rowA = tid >> 2;
  int jA = (tid & 3) ^ (rowA & 3);
  const unsigned short* srcA = xb + (size_t)(n0 + rowA) * H_ + jA * 8;
  const unsigned short* srcB = ewb + (size_t)rowA * H_ + jA * 8;

  gl16(srcA, smem + wv * 1024);
  gl16(srcB, smem + 8192 + wv * 1024);
  __syncthreads();

  f32x4 acc[4] = {};
  int cur = 0;
  for (int ks = 0; ks < H_; ks += 32) {
    if (ks + 32 < H_) {
      gl16(srcA + ks + 32, smem + (cur ^ 1) * 4096 + wv * 1024);
      gl16(srcB + ks + 32, smem + 8192 + (cur ^ 1) * 4096 + wv * 1024);
    }
    int rB = wv * 16 + lo;
    bf16x8 Bf = lds8(smem + 8192 + cur * 4096 + (rB * 4 + (hi ^ (lo & 3))) * 16);
#pragma unroll
    for (int m = 0; m < 4; m++) {
      int row = m * 16 + lo;
      bf16x8 Af = lds8(smem + cur * 4096 + (row * 4 + (hi ^ (lo & 3))) * 16);
      acc[m] = __builtin_amdgcn_mfma_f32_16x16x32_bf16(Af, Bf, acc[m], 0, 0, 0);
    }
    __syncthreads();
    cur ^= 1;
  }

  int r = wv * 16 + lo;
  float eb = enc_b[r];
#pragma unroll
  for (int m = 0; m < 4; m++) {
#pragma unroll
    for (int rg = 0; rg < 4; rg++) {
      int tok = n0 + m * 16 + hi * 4 + rg;
      float v = acc[m][rg] + eb;
      lat[(size_t)tok * R_ + r] = f2bf(v / (1.f + __expf(-v)));
    }
  }
}

__device__ __forceinline__ bool decode_bt(int p, int& b, int& tile) {
  b = (p & 7) + 8 * ((p >> 3) / TILES);
  tile = (p >> 3) % TILES;
  return b < NB_;
}

// ---------------- gateup: pipelined LDS GEMM + MFMA comp ------------------
__global__ __launch_bounds__(256, 3) void gateup_kernel(
    const unsigned short* __restrict__ xb,
    const unsigned short* __restrict__ gwb,
    const unsigned short* __restrict__ uwb,
    const unsigned short* __restrict__ latb,
    const unsigned short* __restrict__ decb_all,
    const float* __restrict__ bbias,
    const float* __restrict__ scale_p,
    const int* __restrict__ counts,
    const int* __restrict__ offsets,
    const int* __restrict__ tok_list,
    const float* __restrict__ wt_list,
    unsigned short* __restrict__ actw) {
  int b, tile;
  if (!decode_bt(blockIdx.x, b, tile)) return;
  int cnt = counts[b];
  int base = tile * MT;
  if (base >= cnt) return;
  int off = offsets[b];

  __shared__ __align__(16) char smem[40960];
  __shared__ float wt_lds[MT];

  int tid = threadIdx.x;
  int wv = tid >> 6, lane = tid & 63;
  int lo = lane & 15, hi = lane >> 4;

  if (tid < MT) {
    int g = base + tid;
    wt_lds[tid] = (g < cnt) ? wt_list[off + g] : 0.f;
  }

  int rowA = tid >> 2;
  int jA = (tid & 3) ^ (rowA & 3);
  int tokA = tok_list[off + min(base + rowA, cnt - 1)];
  const unsigned short* srcA = xb + (size_t)tokA * H_ + jA * 8;

  const unsigned short* gb = gwb + (size_t)b * BS_ * H_;
  const unsigned short* ub = uwb + (size_t)b * BS_ * H_;
  const unsigned short* srcG[2];
  const unsigned short* srcU[2];
#pragma unroll
  for (int s = 0; s < 2; s++) {
    int o = s * 256 + tid;
    int c = o >> 2;
    int j = (o & 3) ^ (c & 3);
    size_t e = (size_t)c * H_ + j * 8;
    srcG[s] = gb + e;
    srcU[s] = ub + e;
  }

  f32x4 accG[4][2] = {};
  f32x4 accU[4][2] = {};

  {
    gl16(srcA, smem + wv * 1024);
#pragma unroll
    for (int s = 0; s < 2; s++) {
      gl16(srcG[s], smem + 8192 + s * 4096 + wv * 1024);
      gl16(srcU[s], smem + 24576 + s * 4096 + wv * 1024);
    }
  }
  __syncthreads();

  int cur = 0;
  for (int ks = 0; ks < H_; ks += 32) {
    if (ks + 32 < H_) {
      int nb_ = cur ^ 1;
      gl16(srcA + ks + 32, smem + nb_ * 4096 + wv * 1024);
#pragma unroll
      for (int s = 0; s < 2; s++) {
        gl16(srcG[s] + ks + 32, smem + 8192 + nb_ * 8192 + s * 4096 + wv * 1024);
        gl16(srcU[s] + ks + 32, smem + 24576 + nb_ * 8192 + s * 4096 + wv * 1024);
      }
    }
    bf16x8 Af[4];
#pragma unroll
    for (int m = 0; m < 4; m++) {
      int row = m * 16 + lo;
      int off16 = row * 4 + (hi ^ (lo & 3));
      Af[m] = lds8(smem + cur * 4096 + off16 * 16);
    }
    bf16x8 Gf[2], Uf[2];
#pragma unroll
    for (int cf = 0; cf < 2; cf++) {
      int c = wv * 32 + cf * 16 + lo;
      int off16 = c * 4 + (hi ^ (lo & 3));
      Gf[cf] = lds8(smem + 8192 + cur * 8192 + off16 * 16);
      Uf[cf] = lds8(smem + 24576 + cur * 8192 + off16 * 16);
    }
#pragma unroll
    for (int m = 0; m < 4; m++) {
#pragma unroll
      for (int cf = 0; cf < 2; cf++) {
        accG[m][cf] = __builtin_amdgcn_mfma_f32_16x16x32_bf16(Af[m], Gf[cf], accG[m][cf], 0, 0, 0);
        accU[m][cf] = __builtin_amdgcn_mfma_f32_16x16x32_bf16(Af[m], Uf[cf], accU[m][cf], 0, 0, 0);
      }
    }
    __syncthreads();
    cur ^= 1;
  }

  // ---- comp GEMM (K=64) ----
#pragma unroll
  for (int s = 0; s < 2; s++) {
    int o = s * 256 + tid;
    int r_ = o >> 3;
    int j = (o & 7) ^ (r_ & 7);
    int tokL = tok_list[off + min(base + r_, cnt - 1)];
    gl16(latb + (size_t)tokL * R_ + j * 8, smem + 24576 + s * 4096 + wv * 1024);
  }
  const unsigned short* decb = decb_all + (size_t)b * BS_ * R_;
#pragma unroll
  for (int s = 0; s < 4; s++) {
    int o = s * 256 + tid;
    int c = o >> 3;
    int j = (o & 7) ^ (c & 7);
    gl16(decb + (size_t)c * R_ + j * 8, smem + 8192 + s * 4096 + wv * 1024);
  }
  __syncthreads();

  f32x4 accC[4][2] = {};
#pragma unroll
  for (int kk = 0; kk < 2; kk++) {
    bf16x8 L[4];
#pragma unroll
    for (int m = 0; m < 4; m++) {
      int row = m * 16 + lo;
      int off16 = row * 8 + ((kk * 4 + hi) ^ (lo & 7));
      L[m] = lds8(smem + 24576 + off16 * 16);
    }
#pragma unroll
    for (int cf = 0; cf < 2; cf++) {
      int c = wv * 32 + cf * 16 + lo;
      int off16 = c * 8 + ((kk * 4 + hi) ^ (lo & 7));
      bf16x8 D = lds8(smem + 8192 + off16 * 16);
#pragma unroll
      for (int m = 0; m < 4; m++)
        accC[m][cf] = __builtin_amdgcn_mfma_f32_16x16x32_bf16(L[m], D, accC[m][cf], 0, 0, 0);
    }
  }

  float scal = scale_p[0];
  int cc[2] = { wv * 32 + lo, wv * 32 + 16 + lo };
  float bbv[2] = { bbias[b * BS_ + cc[0]], bbias[b * BS_ + cc[1]] };
#pragma unroll
  for (int m = 0; m < 4; m++) {
#pragma unroll
    for (int r = 0; r < 4; r++) {
      int t = m * 16 + hi * 4 + r;
      int g = base + t;
      if (g < cnt) {
        float wt = wt_lds[t];
        unsigned short* dst = actw + (size_t)(off + g) * BS_;
#pragma unroll
        for (int cf = 0; cf < 2; cf++) {
          float gg = accG[m][cf][r];
          float uu = accU[m][cf][r];
          float act = (gg / (1.f + __expf(-gg))) * uu;
          dst[cc[cf]] = f2bf((act + scal * (accC[m][cf][r] + bbv[cf])) * wt);
        }
      }
    }
  }
}

// ---------------- down: LDS-staged B, reg-cached act, chunked H -----------
// LDS: a_lds 16KB + b_lds dbuf 2x16KB = 48KB -> 3 wgs/CU
__global__ __launch_bounds__(256) void down_kernel(
    const unsigned short* __restrict__ actw,
    const unsigned short* __restrict__ dwb,
    const int* __restrict__ counts,
    const int* __restrict__ offsets,
    unsigned short* __restrict__ partial,
    int hc0, int Hc) {
  int b, tile;
  if (!decode_bt(blockIdx.x, b, tile)) return;
  int cnt = counts[b];
  int base = tile * MT;
  if (base >= cnt) return;
  int off = offsets[b];

  __shared__ __align__(16) unsigned short a_lds[MT * BS_];
  __shared__ __align__(16) char b_lds[2][16384];
  int tid = threadIdx.x;
  int wv = tid >> 6, lane = tid & 63;
  int lo = lane & 15, hi = lane >> 4;

  // stage act tile (64 slots x 128), XOR-swizzled over 8-chunk groups
  for (int i = tid; i < MT * BS_ / 8; i += 256) {
    int t = i >> 4, cb = i & 15;
    int g = base + t;
    uint4 v = make_uint4(0, 0, 0, 0);
    if (g < cnt) v = *(const uint4*)(actw + (size_t)(off + g) * BS_ + cb * 8);
    *(uint4*)(&a_lds[t * BS_ + ((cb ^ (t & 7)) << 3)]) = v;
  }
  __syncthreads();

  // hoist act fragments to registers (loop-invariant over h)
  bf16x8 Bf[4][4];
#pragma unroll
  for (int kst = 0; kst < 4; kst++)
#pragma unroll
    for (int sf = 0; sf < 4; sf++) {
      int t = sf * 16 + lo, cb = kst * 4 + hi;
      Bf[kst][sf] = ld8(&a_lds[t * BS_ + ((cb ^ (t & 7)) << 3)]);
    }

  const unsigned short* db = dwb + (size_t)b * H_ * BS_;
  int rs = tid >> 4;      // row within 16-row staging round
  int jc = tid & 15;      // chunk column
  {
    const unsigned short* d0 = db + (size_t)hc0 * BS_;
#pragma unroll
    for (int s = 0; s < 4; s++) {
      int r = s * 16 + rs;
      int j = jc ^ (r & 15);
      gl16(d0 + (size_t)r * BS_ + j * 8, b_lds[0] + s * 4096 + wv * 1024);
    }
  }
  __syncthreads();

  int nit = Hc >> 6;
  int cur = 0;
  for (int it = 0; it < nit; it++) {
    if (it + 1 < nit) {
      const unsigned short* dn = db + (size_t)(hc0 + (it + 1) * 64) * BS_;
#pragma unroll
      for (int s = 0; s < 4; s++) {
        int r = s * 16 + rs;
        int j = jc ^ (r & 15);
        gl16(dn + (size_t)r * BS_ + j * 8, b_lds[cur ^ 1] + s * 4096 + wv * 1024);
      }
    }
    f32x4 acc[4] = {};
    int rl = wv * 16 + lo;
#pragma unroll
    for (int kst = 0; kst < 4; kst++) {
      int cb = kst * 4 + hi;
      bf16x8 Aw = lds8(b_lds[cur] + (rl * 16 + (cb ^ lo)) * 16);
#pragma unroll
      for (int sf = 0; sf < 4; sf++)
        acc[sf] = __builtin_amdgcn_mfma_f32_16x16x32_bf16(Aw, Bf[kst][sf], acc[sf], 0, 0, 0);
    }
    int hrel = it * 64 + wv * 16 + hi * 4;
#pragma unroll
    for (int sf = 0; sf < 4; sf++) {
      int g = base + sf * 16 + lo;
      if (g < cnt) {
        uint2 pk;
        pk.x = (unsigned int)f2bf(acc[sf][0]) | ((unsigned int)f2bf(acc[sf][1]) << 16);
        pk.y = (unsigned int)f2bf(acc[sf][2]) | ((unsigned int)f2bf(acc[sf][3]) << 16);
        *(uint2*)(partial + (size_t)(off + g) * Hc + hrel) = pk;
      }
    }
    __syncthreads();
    cur ^= 1;
  }
}

// ---------------- reduce ---------------------------------------------------
__global__ __launch_bounds__(256) void reduce_kernel(
    const unsigned short* __restrict__ partial,
    const int* __restrict__ inv,
    const float* __restrict__ cbias,
    float* __restrict__ out, int hc0, int Hc) {
  int wv = threadIdx.x >> 6, l = threadIdx.x & 63;
  int n = blockIdx.x * 4 + wv;
  int rows[K_];
#pragma unroll
  for (int k = 0; k < K_; k++) rows[k] = inv[n * K_ + k];
  for (int c0w = 0; c0w < Hc; c0w += 512) {
    int cw = c0w + l * 8;
    if (cw >= Hc) continue;
    float a[8] = {0.f, 0.f, 0.f, 0.f, 0.f, 0.f, 0.f, 0.f};
#pragma unroll
    for (int k = 0; k < K_; k++) {
      uint4 v = *(const uint4*)(partial + (size_t)rows[k] * Hc + cw);
      unsigned int w0 = v.x, w1 = v.y, w2 = v.z, w3 = v.w;
      a[0] += __uint_as_float(w0 << 16); a[1] += __uint_as_float(w0 & 0xFFFF0000u);
      a[2] += __uint_as_float(w1 << 16); a[3] += __uint_as_float(w1 & 0xFFFF0000u);
      a[4] += __uint_as_float(w2 << 16); a[5] += __uint_as_float(w2 & 0xFFFF0000u);
      a[6] += __uint_as_float(w3 << 16); a[7] += __uint_as_float(w3 & 0xFFFF0000u);
    }
    int h = hc0 + cw;
    float4 c0 = *(const float4*)(cbias + h);
    float4 c1 = *(const float4*)(cbias + h + 4);
    float4 o0 = make_float4(a[0] + c0.x, a[1] + c0.y, a[2] + c0.z, a[3] + c0.w);
    float4 o1 = make_float4(a[4] + c1.x, a[5] + c1.y, a[6] + c1.z, a[7] + c1.w);
    *(float4*)(out + (size_t)n * H_ + h) = o0;
    *(float4*)(out + (size_t)n * H_ + h + 4) = o1;
  }
}

// ---------------- launch ---------------------------------------------------
extern "C" void kernel_launch(void* const* d_in, const int* in_sizes, int n_in,
                              void* d_out, int out_size, void* d_ws, size_t ws_size,
                              hipStream_t stream) {
  const float* x       = (const float*)d_in[0];
  const int*   aidx    = (const int*)d_in[1];
  const float* score   = (const float*)d_in[2];
  const float* gate_w  = (const float*)d_in[3];
  const float* up_w    = (const float*)d_in[4];
  const float* down_w  = (const float*)d_in[5];
  const float* enc_w   = (const float*)d_in[6];
  const float* enc_b   = (const float*)d_in[7];
  const float* decoder = (const float*)d_in[8];
  const float* bbias   = (const float*)d_in[9];
  const float* cbias   = (const float*)d_in[10];
  const float* scale   = (const float*)d_in[11];
  float* out = (float*)d_out;

  char* ws = (char*)d_ws;
  const size_t OFF_GWB  = 33554432ull;
  const size_t OFF_UWB  = 56623104ull;
  const size_t OFF_DEC  = 79691776ull;
  const size_t OFF_LATB = 80412672ull;
  const size_t OFF_ENCB = 81461248ull;
  const size_t OFF_WBUF = 81723392ull;
  const size_t OFF_TOK  = 81985536ull;
  const size_t OFF_WT   = 82247680ull;
  const size_t OFF_INV  = 82509824ull;
  const size_t OFF_CNT  = 82771968ull;
  const size_t OFF_ACTW = 82772992ull;
  const size_t BASE_END = 99550208ull;
  const size_t DWB_SZ   = 23068672ull;

  unsigned short* xb   = (unsigned short*)(ws);
  unsigned short* gwb  = (unsigned short*)(ws + OFF_GWB);
  unsigned short* uwb  = (unsigned short*)(ws + OFF_UWB);
  unsigned short* decb = (unsigned short*)(ws + OFF_DEC);
  unsigned short* latb = (unsigned short*)(ws + OFF_LATB);
  unsigned short* ewb  = (unsigned short*)(ws + OFF_ENCB);
  float* w_buf         = (float*)(ws + OFF_WBUF);
  int*   tok_list      = (int*)(ws + OFF_TOK);
  float* wt_list       = (float*)(ws + OFF_WT);
  int*   inv           = (int*)(ws + OFF_INV);
  int*   counts        = (int*)(ws + OFF_CNT);
  int*   offsets       = counts + 64;
  int*   cursors       = counts + 128;
  unsigned short* actw = (unsigned short*)(ws + OFF_ACTW);

  // partial chunk: prefer Hc=512 (67 MB chunk -> L3-resident round-trip)
  int Hc; unsigned short* dwb; unsigned short* partial; bool early_down;
  if      (ws_size >= BASE_END + DWB_SZ + 131072ull * 512) Hc = 512;
  else if (ws_size >= BASE_END + DWB_SZ + 131072ull * 256) Hc = 256;
  else Hc = 0;
  if (Hc) {
    early_down = true;
    dwb = (unsigned short*)(ws + BASE_END);
    partial = (unsigned short*)(ws + BASE_END + DWB_SZ);
  } else {
    early_down = false;
    Hc = 256;
    dwb = gwb;
    partial = (unsigned short*)ws;
  }
  int nch = H_ / Hc;

  cvt_xgu<<<2048, 256, 0, stream>>>(x, gate_w, up_w, enc_w, xb, gwb, uwb, ewb);
  cvt_dec<<<(NB_ * BS_ * R_ + 255) / 256, 256, 0, stream>>>(decoder, decb);
  if (early_down) cvt_down<<<2048, 256, 0, stream>>>(down_w, dwb);
  zero_counts<<<1, 64, 0, stream>>>(counts);
  prep_kernel<<<N_ / 256, 256, 0, stream>>>(score, aidx, w_buf, counts);
  scan_kernel<<<1, 64, 0, stream>>>(counts, offsets, cursors);
  fill_kernel<<<N_ / 256, 256, 0, stream>>>(aidx, w_buf, cursors, tok_list, wt_list, inv);
  latent_mfma<<<N_ / 64, 256, 0, stream>>>(xb, ewb, enc_b, latb);
  gateup_kernel<<<GRID_AB, 256, 0, stream>>>(xb, gwb, uwb, latb, decb, bbias, scale,
                                             counts, offsets, tok_list, wt_list, actw);
  if (!early_down) cvt_down<<<2048, 256, 0, stream>>>(down_w, dwb);
  for (int c = 0; c < nch; c++) {
    down_kernel<<<GRID_AB, 256, 0, stream>>>(actw, dwb, counts, offsets, partial, c * Hc, Hc);
    reduce_kernel<<<N_ / 4, 256, 0, stream>>>(partial, inv, cbias, out, c * Hc, Hc);
  }
}